// Round 4
// baseline (616.619 us; speedup 1.0000x reference)
//
#include <hip/hip_runtime.h>
#include <hip/hip_bf16.h>
#include <math.h>

#define D 128
#define SCALE 0.25f

typedef __attribute__((ext_vector_type(8))) short bf16x8;
typedef __attribute__((ext_vector_type(4))) float f32x4;

// ---------------------------------------------------------------------------
// edge_index dtype detection (int64 vs int32) — round-0 notes.
__global__ void detect_i64(const int* __restrict__ ei, int* __restrict__ flag) {
    __shared__ int cnt;
    if (threadIdx.x == 0) cnt = 0;
    __syncthreads();
    int v = ei[2 * threadIdx.x + 1];
    if (v != 0) atomicAdd(&cnt, 1);
    __syncthreads();
    if (threadIdx.x == 0) flag[0] = (cnt == 0) ? 1 : 0;
}

__global__ void zero_ints(int* __restrict__ p, int n) {
    int i = blockIdx.x * blockDim.x + threadIdx.x;
    if (i < n) p[i] = 0;
}

__global__ void count_deg(const int* __restrict__ ei, int E,
                          const int* __restrict__ flag, int* __restrict__ deg) {
    int e = blockIdx.x * blockDim.x + threadIdx.x;
    if (e >= E) return;
    int is64 = flag[0];
    int d = is64 ? ei[2 * E + 2 * e] : ei[E + e];
    atomicAdd(&deg[d], 1);
}

// ---- 3-phase device-wide exclusive scan
__global__ __launch_bounds__(1024) void scan_blocks(const int* __restrict__ deg,
                                                    int* __restrict__ row_ptr,
                                                    int* __restrict__ bsum, int Nn) {
    __shared__ int buf[1024];
    int tid = threadIdx.x;
    int i = blockIdx.x * 1024 + tid;
    int v = (i < Nn) ? deg[i] : 0;
    buf[tid] = v;
    __syncthreads();
    for (int off = 1; off < 1024; off <<= 1) {
        int t = (tid >= off) ? buf[tid - off] : 0;
        __syncthreads();
        buf[tid] += t;
        __syncthreads();
    }
    if (i < Nn) row_ptr[i] = buf[tid] - v;
    if (tid == 1023) bsum[blockIdx.x] = buf[1023];
}

__global__ __launch_bounds__(1024) void scan_bsum(int* __restrict__ bsum,
                                                  int* __restrict__ boff,
                                                  int NB, int* __restrict__ row_ptr, int Nn) {
    __shared__ int buf[1024];
    int tid = threadIdx.x;
    int v = (tid < NB) ? bsum[tid] : 0;
    buf[tid] = v;
    __syncthreads();
    for (int off = 1; off < 1024; off <<= 1) {
        int t = (tid >= off) ? buf[tid - off] : 0;
        __syncthreads();
        buf[tid] += t;
        __syncthreads();
    }
    if (tid < NB) boff[tid] = buf[tid] - v;
    if (tid == 0) row_ptr[Nn] = buf[NB - 1];
}

__global__ void add_offsets(int* __restrict__ row_ptr, int* __restrict__ cursor,
                            const int* __restrict__ boff, int Nn) {
    int i = blockIdx.x * blockDim.x + threadIdx.x;
    if (i < Nn) {
        int r = row_ptr[i] + boff[i >> 10];
        row_ptr[i] = r;
        cursor[i] = r;
    }
}

__global__ void scatter_edges(const int* __restrict__ ei, int E,
                              const int* __restrict__ flag,
                              int* __restrict__ cursor, int* __restrict__ srcs) {
    int e = blockIdx.x * blockDim.x + threadIdx.x;
    if (e >= E) return;
    int is64 = flag[0];
    int s = is64 ? ei[2 * e]         : ei[e];
    int d = is64 ? ei[2 * E + 2 * e] : ei[E + e];
    int pos = atomicAdd(&cursor[d], 1);
    srcs[pos] = s;
}

// ---------------------------------------------------------------------------
struct PackArgs { const float* w[8]; };

__global__ __launch_bounds__(256) void pack_w(PackArgs pa, __hip_bfloat16* __restrict__ out) {
    int b = blockIdx.x;
    const float* W = pa.w[b];
    __hip_bfloat16* dst = out + (size_t)b * 128 * 128;
    for (int idx = threadIdx.x; idx < 128 * 128; idx += 256) {
        int c = idx & 127, k = idx >> 7;
        dst[(size_t)c * 128 + k] = __float2bfloat16(W[(size_t)k * 128 + c]);
    }
}

__global__ void f32_to_bf16(const float* __restrict__ in, __hip_bfloat16* __restrict__ out, int n4) {
    int i = blockIdx.x * blockDim.x + threadIdx.x;
    if (i >= n4) return;
    float4 v = ((const float4*)in)[i];
    __hip_bfloat162 a, b;
    a.x = __float2bfloat16(v.x); a.y = __float2bfloat16(v.y);
    b.x = __float2bfloat16(v.z); b.y = __float2bfloat16(v.w);
    ((__hip_bfloat162*)out)[2 * i]     = a;
    ((__hip_bfloat162*)out)[2 * i + 1] = b;
}

__device__ inline __hip_bfloat162 pack2(float a, float b) {
    __hip_bfloat162 h;
    h.x = __float2bfloat16(a);
    h.y = __float2bfloat16(b);
    return h;
}

// ---------------------------------------------------------------------------
// Fused 4-way GEMM with operand-swapped MFMA (transposed C/D roles):
// lane's 4 acc elements = 4 consecutive OUTPUT COLUMNS of one row -> packed
// bf16 vector stores. Outputs: qb bf16 [M,128], kv bf16 [M,256] interleaved
// per pair [k2p,k2p+1,v2p,v2p+1], skipb bf16 [M,128].
__global__ __launch_bounds__(256) void gemm_mfma(
    const __hip_bfloat16* __restrict__ A,   // [M,128]
    const __hip_bfloat16* __restrict__ Wt,  // [512,128] (col,k)
    const float* __restrict__ bq, const float* __restrict__ bk,
    const float* __restrict__ bv, const float* __restrict__ bs,
    __hip_bfloat16* __restrict__ qb, __hip_bfloat16* __restrict__ kv,
    __hip_bfloat16* __restrict__ skipb, int M)
{
    const int tid = threadIdx.x;
    const int w = tid >> 6, lane = tid & 63;
    const int wr = w >> 1, wc = w & 1;
    const int rowBase = blockIdx.x * 64 + wr * 32;
    const int l16 = lane & 15;
    const int quad = lane >> 4;

    // X fragments (second MFMA operand): 2 row-tiles x 4 kb, held in regs
    bf16x8 xfrag[2][4];
    #pragma unroll
    for (int i = 0; i < 2; ++i) {
        int r = rowBase + i * 16 + l16;
        if (r >= M) r = M - 1;
        #pragma unroll
        for (int kb = 0; kb < 4; ++kb)
            xfrag[i][kb] = *(const bf16x8*)(A + (size_t)r * D + kb * 32 + quad * 8);
    }

    const float* biases[4] = {bq, bk, bv, bs};

    #pragma unroll
    for (int cb = 0; cb < 4; ++cb) {
        const __hip_bfloat16* Wblk = Wt + (size_t)cb * 128 * 128;
        f32x4 acc[2][4];
        #pragma unroll
        for (int i = 0; i < 2; i++)
            #pragma unroll
            for (int jt = 0; jt < 4; jt++) acc[i][jt] = (f32x4){0.f, 0.f, 0.f, 0.f};

        #pragma unroll
        for (int kb = 0; kb < 4; ++kb) {
            const int k0 = kb * 32 + quad * 8;
            #pragma unroll
            for (int jt = 0; jt < 4; ++jt) {
                int c = wc * 64 + jt * 16 + l16;
                bf16x8 wfrag = *(const bf16x8*)(Wblk + (size_t)c * D + k0);
                // swapped operands: M-role = W cols, N-role = X rows
                acc[0][jt] = __builtin_amdgcn_mfma_f32_16x16x32_bf16(wfrag, xfrag[0][kb], acc[0][jt], 0, 0, 0);
                acc[1][jt] = __builtin_amdgcn_mfma_f32_16x16x32_bf16(wfrag, xfrag[1][kb], acc[1][jt], 0, 0, 0);
            }
        }

        const float* bias = biases[cb];
        #pragma unroll
        for (int jt = 0; jt < 4; ++jt) {
            int c0 = wc * 64 + jt * 16 + quad * 4;    // 4 consecutive output cols
            float4 bb = *(const float4*)(bias + c0);
            #pragma unroll
            for (int i = 0; i < 2; ++i) {
                int orow = rowBase + i * 16 + l16;     // output row = X row (l16)
                if (orow >= M) continue;
                f32x4 v = acc[i][jt];
                float e0 = v[0] + bb.x, e1 = v[1] + bb.y;
                float e2 = v[2] + bb.z, e3 = v[3] + bb.w;
                __hip_bfloat162 h0 = pack2(e0, e1), h1 = pack2(e2, e3);
                if (cb == 0) {
                    float2 st; st.x = *(float*)&h0; st.y = *(float*)&h1;
                    *(float2*)(qb + (size_t)orow * D + c0) = st;
                } else if (cb == 1) {       // k: pair p -> row offset 4p
                    *(float*)(kv + (size_t)orow * 256 + 2 * c0)     = *(float*)&h0;
                    *(float*)(kv + (size_t)orow * 256 + 2 * c0 + 4) = *(float*)&h1;
                } else if (cb == 2) {       // v: pair p -> row offset 4p + 2
                    *(float*)(kv + (size_t)orow * 256 + 2 * c0 + 2) = *(float*)&h0;
                    *(float*)(kv + (size_t)orow * 256 + 2 * c0 + 6) = *(float*)&h1;
                } else {
                    float2 st; st.x = *(float*)&h0; st.y = *(float*)&h1;
                    *(float2*)(skipb + (size_t)orow * D + c0) = st;
                }
            }
        }
    }
}

// ---------------------------------------------------------------------------
// One wave per dst node, online softmax. Lane l holds dims {2l,2l+1};
// head = l>>3, dot reduced over 8 lanes. One dwordx2 kv load per edge.
// Main loop batch-8 unmasked, tail batch-4 masked (clamped dup loads hit L1).
__device__ inline void store_pair(float* base, int idx, float o0, float o1) {
    ((float2*)base)[idx] = make_float2(o0, o1);
}
__device__ inline void store_pair(__hip_bfloat16* base, int idx, float o0, float o1) {
    ((__hip_bfloat162*)base)[idx] = pack2(o0, o1);
}

template <typename OutT>
__global__ __launch_bounds__(256) void attn_agg(
    const __hip_bfloat16* __restrict__ qb, const __hip_bfloat16* __restrict__ kv,
    const int* __restrict__ row_ptr, const int* __restrict__ srcs,
    const __hip_bfloat16* __restrict__ skip, const float* __restrict__ resid,
    const float* __restrict__ a_ptr, OutT* __restrict__ out, int Nn) {
    int n = blockIdx.x * 4 + (threadIdx.x >> 6);
    if (n >= Nn) return;
    int lane = threadIdx.x & 63;
    const float a = a_ptr[0];

    __hip_bfloat162 qp = ((const __hip_bfloat162*)(qb + (size_t)n * D))[lane];
    float qx = __bfloat162float(qp.x), qy = __bfloat162float(qp.y);
    float m = -INFINITY, s = 0.f, a0 = 0.f, a1 = 0.f;

    int beg = __builtin_amdgcn_readfirstlane(row_ptr[n]);
    int end = __builtin_amdgcn_readfirstlane(row_ptr[n + 1]);
    const float2* kvp = (const float2*)kv;

    int j = beg;
    for (; j + 8 <= end; j += 8) {
        float2 f[8];
        float sc[8];
        #pragma unroll
        for (int i = 0; i < 8; ++i) {
            int src = srcs[j + i];                       // wave-uniform -> s_load
            f[i] = kvp[(size_t)src * 64 + lane];
        }
        #pragma unroll
        for (int i = 0; i < 8; ++i) {
            __hip_bfloat162 kp = *(__hip_bfloat162*)&f[i].x;
            float p = qx * __bfloat162float(kp.x) + qy * __bfloat162float(kp.y);
            p += __shfl_xor(p, 1);
            p += __shfl_xor(p, 2);
            p += __shfl_xor(p, 4);
            sc[i] = p * SCALE;
        }
        float nm = m;
        #pragma unroll
        for (int i = 0; i < 8; ++i) nm = fmaxf(nm, sc[i]);
        float corr = __expf(m - nm);
        a0 *= corr; a1 *= corr; s *= corr;
        #pragma unroll
        for (int i = 0; i < 8; ++i) {
            float wgt = __expf(sc[i] - nm);
            __hip_bfloat162 vp = *(__hip_bfloat162*)&f[i].y;
            a0 += wgt * __bfloat162float(vp.x);
            a1 += wgt * __bfloat162float(vp.y);
            s += wgt;
        }
        m = nm;
    }
    for (; j < end; j += 4) {                             // masked tail
        float2 f[4];
        float sc[4];
        #pragma unroll
        for (int i = 0; i < 4; ++i) {
            int jj = j + i; if (jj > end - 1) jj = end - 1;
            int src = srcs[jj];
            f[i] = kvp[(size_t)src * 64 + lane];
        }
        #pragma unroll
        for (int i = 0; i < 4; ++i) {
            __hip_bfloat162 kp = *(__hip_bfloat162*)&f[i].x;
            float p = qx * __bfloat162float(kp.x) + qy * __bfloat162float(kp.y);
            p += __shfl_xor(p, 1);
            p += __shfl_xor(p, 2);
            p += __shfl_xor(p, 4);
            sc[i] = (j + i < end) ? p * SCALE : -INFINITY;
        }
        float nm = m;
        #pragma unroll
        for (int i = 0; i < 4; ++i) nm = fmaxf(nm, sc[i]);
        float corr = __expf(m - nm);
        a0 *= corr; a1 *= corr; s *= corr;
        #pragma unroll
        for (int i = 0; i < 4; ++i) {
            float wgt = __expf(sc[i] - nm);
            __hip_bfloat162 vp = *(__hip_bfloat162*)&f[i].y;
            a0 += wgt * __bfloat162float(vp.x);
            a1 += wgt * __bfloat162float(vp.y);
            s += wgt;
        }
        m = nm;
    }

    float inv = (end > beg) ? 1.f / s : 0.f;
    __hip_bfloat162 skp = ((const __hip_bfloat162*)(skip + (size_t)n * D))[lane];
    float o0 = a0 * inv + __bfloat162float(skp.x);
    float o1 = a1 * inv + __bfloat162float(skp.y);
    if (resid) {
        float2 rs = ((const float2*)(resid + (size_t)n * D))[lane];
        o0 += rs.x; o1 += rs.y;
    }
    o0 = (o0 >= 0.f) ? o0 : a * o0;
    o1 = (o1 >= 0.f) ? o1 : a * o1;
    store_pair(out, n * (D / 2) + lane, o0, o1);
}

// ---------------------------------------------------------------------------
extern "C" void kernel_launch(void* const* d_in, const int* in_sizes, int n_in,
                              void* d_out, int out_size, void* d_ws, size_t ws_size,
                              hipStream_t stream) {
    const float* x  = (const float*)d_in[0];
    const int*   ei = (const int*)d_in[1];
    const float* a  = (const float*)d_in[2];
    const float* Wq1 = (const float*)d_in[3];  const float* bq1 = (const float*)d_in[4];
    const float* Wk1 = (const float*)d_in[5];  const float* bk1 = (const float*)d_in[6];
    const float* Wv1 = (const float*)d_in[7];  const float* bv1 = (const float*)d_in[8];
    const float* Ws1 = (const float*)d_in[9];  const float* bs1 = (const float*)d_in[10];
    const float* Wq2 = (const float*)d_in[11]; const float* bq2 = (const float*)d_in[12];
    const float* Wk2 = (const float*)d_in[13]; const float* bk2 = (const float*)d_in[14];
    const float* Wv2 = (const float*)d_in[15]; const float* bv2 = (const float*)d_in[16];
    const float* Ws2 = (const float*)d_in[17]; const float* bs2 = (const float*)d_in[18];

    const int N = in_sizes[0] / D;        // 100000
    const int E = in_sizes[1] / 2;        // 1000000
    const size_t NF = (size_t)N * D;

    char* wp = (char*)d_ws;
    __hip_bfloat16* xb    = (__hip_bfloat16*)wp; wp += NF * 2;
    __hip_bfloat16* h1b   = (__hip_bfloat16*)wp; wp += NF * 2;
    __hip_bfloat16* qb    = (__hip_bfloat16*)wp; wp += NF * 2;
    __hip_bfloat16* kv    = (__hip_bfloat16*)wp; wp += NF * 4;   // [N,256] pair-interleaved
    __hip_bfloat16* skipb = (__hip_bfloat16*)wp; wp += NF * 2;
    __hip_bfloat16* WtP   = (__hip_bfloat16*)wp; wp += 2 * 512 * 128 * 2;
    int* flag    = (int*)wp;  wp += 64;
    int* deg     = (int*)wp;  wp += (size_t)N * 4;
    int* row_ptr = (int*)wp;  wp += (size_t)(N + 64) * 4;
    int* cursor  = (int*)wp;  wp += (size_t)N * 4;
    int* bsum    = (int*)wp;  wp += 1024 * 4;
    int* boff    = (int*)wp;  wp += 1024 * 4;
    int* srcs    = (int*)wp;  wp += (size_t)E * 4;
    float* out   = (float*)d_out;

    const int TB = 256;
    int gN = (N + TB - 1) / TB;
    int gE = (E + TB - 1) / TB;
    int NB = (N + 1023) / 1024;
    int gGemm = (N + 63) / 64;
    int gAttn = (N + 3) / 4;
    int gCvt  = ((int)(NF / 4) + TB - 1) / TB;

    // ---- CSR build ----
    hipLaunchKernelGGL(detect_i64, dim3(1), dim3(1024), 0, stream, ei, flag);
    hipLaunchKernelGGL(zero_ints, dim3(gN), dim3(TB), 0, stream, deg, N);
    hipLaunchKernelGGL(count_deg, dim3(gE), dim3(TB), 0, stream, ei, E, flag, deg);
    hipLaunchKernelGGL(scan_blocks, dim3(NB), dim3(1024), 0, stream, deg, row_ptr, bsum, N);
    hipLaunchKernelGGL(scan_bsum, dim3(1), dim3(1024), 0, stream, bsum, boff, NB, row_ptr, N);
    hipLaunchKernelGGL(add_offsets, dim3(gN), dim3(TB), 0, stream, row_ptr, cursor, boff, N);
    hipLaunchKernelGGL(scatter_edges, dim3(gE), dim3(TB), 0, stream, ei, E, flag, cursor, srcs);

    // ---- weight pack + input convert ----
    PackArgs pa;
    pa.w[0] = Wq1; pa.w[1] = Wk1; pa.w[2] = Wv1; pa.w[3] = Ws1;
    pa.w[4] = Wq2; pa.w[5] = Wk2; pa.w[6] = Wv2; pa.w[7] = Ws2;
    hipLaunchKernelGGL(pack_w, dim3(8), dim3(TB), 0, stream, pa, WtP);
    hipLaunchKernelGGL(f32_to_bf16, dim3(gCvt), dim3(TB), 0, stream, x, xb, (int)(NF / 4));

    // ---- layer 1 ----
    hipLaunchKernelGGL(gemm_mfma, dim3(gGemm), dim3(TB), 0, stream,
                       xb, WtP, bq1, bk1, bv1, bs1, qb, kv, skipb, N);
    hipLaunchKernelGGL(attn_agg<__hip_bfloat16>, dim3(gAttn), dim3(TB), 0, stream,
                       qb, kv, row_ptr, srcs, skipb, (const float*)nullptr, a, h1b, N);

    // ---- layer 2 ----
    hipLaunchKernelGGL(gemm_mfma, dim3(gGemm), dim3(TB), 0, stream,
                       h1b, WtP + 512 * 128, bq2, bk2, bv2, bs2, qb, kv, skipb, N);
    hipLaunchKernelGGL(attn_agg<float>, dim3(gAttn), dim3(TB), 0, stream,
                       qb, kv, row_ptr, srcs, skipb, x, a, out, N);
}

// Round 5
// 597.774 us; speedup vs baseline: 1.0315x; 1.0315x over previous
//
#include <hip/hip_runtime.h>
#include <hip/hip_bf16.h>
#include <math.h>

#define D 128
#define SCALE 0.25f

typedef __attribute__((ext_vector_type(8))) short bf16x8;
typedef __attribute__((ext_vector_type(4))) float f32x4;

// ---------------------------------------------------------------------------
// edge_index dtype detection (int64 vs int32) — round-0 notes.
__global__ void detect_i64(const int* __restrict__ ei, int* __restrict__ flag) {
    __shared__ int cnt;
    if (threadIdx.x == 0) cnt = 0;
    __syncthreads();
    int v = ei[2 * threadIdx.x + 1];
    if (v != 0) atomicAdd(&cnt, 1);
    __syncthreads();
    if (threadIdx.x == 0) flag[0] = (cnt == 0) ? 1 : 0;
}

__global__ void zero_ints(int* __restrict__ p, int n) {
    int i = blockIdx.x * blockDim.x + threadIdx.x;
    if (i < n) p[i] = 0;
}

__global__ void count_deg(const int* __restrict__ ei, int E,
                          const int* __restrict__ flag, int* __restrict__ deg) {
    int e = blockIdx.x * blockDim.x + threadIdx.x;
    if (e >= E) return;
    int is64 = flag[0];
    int d = is64 ? ei[2 * E + 2 * e] : ei[E + e];
    atomicAdd(&deg[d], 1);
}

// ---- 3-phase device-wide exclusive scan
__global__ __launch_bounds__(1024) void scan_blocks(const int* __restrict__ deg,
                                                    int* __restrict__ row_ptr,
                                                    int* __restrict__ bsum, int Nn) {
    __shared__ int buf[1024];
    int tid = threadIdx.x;
    int i = blockIdx.x * 1024 + tid;
    int v = (i < Nn) ? deg[i] : 0;
    buf[tid] = v;
    __syncthreads();
    for (int off = 1; off < 1024; off <<= 1) {
        int t = (tid >= off) ? buf[tid - off] : 0;
        __syncthreads();
        buf[tid] += t;
        __syncthreads();
    }
    if (i < Nn) row_ptr[i] = buf[tid] - v;
    if (tid == 1023) bsum[blockIdx.x] = buf[1023];
}

__global__ __launch_bounds__(1024) void scan_bsum(int* __restrict__ bsum,
                                                  int* __restrict__ boff,
                                                  int NB, int* __restrict__ row_ptr, int Nn) {
    __shared__ int buf[1024];
    int tid = threadIdx.x;
    int v = (tid < NB) ? bsum[tid] : 0;
    buf[tid] = v;
    __syncthreads();
    for (int off = 1; off < 1024; off <<= 1) {
        int t = (tid >= off) ? buf[tid - off] : 0;
        __syncthreads();
        buf[tid] += t;
        __syncthreads();
    }
    if (tid < NB) boff[tid] = buf[tid] - v;
    if (tid == 0) row_ptr[Nn] = buf[NB - 1];
}

__global__ void add_offsets(int* __restrict__ row_ptr, int* __restrict__ cursor,
                            const int* __restrict__ boff, int Nn) {
    int i = blockIdx.x * blockDim.x + threadIdx.x;
    if (i < Nn) {
        int r = row_ptr[i] + boff[i >> 10];
        row_ptr[i] = r;
        cursor[i] = r;
    }
}

__global__ void scatter_edges(const int* __restrict__ ei, int E,
                              const int* __restrict__ flag,
                              int* __restrict__ cursor, int* __restrict__ srcs) {
    int e = blockIdx.x * blockDim.x + threadIdx.x;
    if (e >= E) return;
    int is64 = flag[0];
    int s = is64 ? ei[2 * e]         : ei[e];
    int d = is64 ? ei[2 * E + 2 * e] : ei[E + e];
    int pos = atomicAdd(&cursor[d], 1);
    srcs[pos] = s;
}

// ---------------------------------------------------------------------------
struct PackArgs { const float* w[8]; };

__global__ __launch_bounds__(256) void pack_w(PackArgs pa, __hip_bfloat16* __restrict__ out) {
    int b = blockIdx.x;
    const float* W = pa.w[b];
    __hip_bfloat16* dst = out + (size_t)b * 128 * 128;
    for (int idx = threadIdx.x; idx < 128 * 128; idx += 256) {
        int c = idx & 127, k = idx >> 7;
        dst[(size_t)c * 128 + k] = __float2bfloat16(W[(size_t)k * 128 + c]);
    }
}

__global__ void f32_to_bf16(const float* __restrict__ in, __hip_bfloat16* __restrict__ out, int n4) {
    int i = blockIdx.x * blockDim.x + threadIdx.x;
    if (i >= n4) return;
    float4 v = ((const float4*)in)[i];
    __hip_bfloat162 a, b;
    a.x = __float2bfloat16(v.x); a.y = __float2bfloat16(v.y);
    b.x = __float2bfloat16(v.z); b.y = __float2bfloat16(v.w);
    ((__hip_bfloat162*)out)[2 * i]     = a;
    ((__hip_bfloat162*)out)[2 * i + 1] = b;
}

__device__ inline __hip_bfloat162 pack2(float a, float b) {
    __hip_bfloat162 h;
    h.x = __float2bfloat16(a);
    h.y = __float2bfloat16(b);
    return h;
}

// ---------------------------------------------------------------------------
// Fused 4-way GEMM, swapped-operand MFMA (lane holds 4 consecutive output
// cols of one row), epilogue staged through LDS for fully coalesced stores.
// LDS tile stride 136 bf16 (272 B): 16 B-aligned rows, low bank conflict.
#define TSTR 136

__global__ __launch_bounds__(256) void gemm_mfma(
    const __hip_bfloat16* __restrict__ A,   // [M,128]
    const __hip_bfloat16* __restrict__ Wt,  // [512,128] (col,k)
    const float* __restrict__ bq, const float* __restrict__ bk,
    const float* __restrict__ bv, const float* __restrict__ bs,
    __hip_bfloat16* __restrict__ qb, __hip_bfloat16* __restrict__ kv,
    __hip_bfloat16* __restrict__ skipb, int M)
{
    __shared__ __hip_bfloat16 bufA[64 * TSTR];
    __shared__ __hip_bfloat16 bufB[64 * TSTR];

    const int tid = threadIdx.x;
    const int w = tid >> 6, lane = tid & 63;
    const int wr = w >> 1, wc = w & 1;
    const int blk0 = blockIdx.x * 64;          // block's first row
    const int rowBase = blk0 + wr * 32;        // wave's first row (wave covers 32 rows)
    const int l16 = lane & 15;
    const int quad = lane >> 4;

    // X fragments (second MFMA operand): 2 row-tiles x 4 kb, held in regs
    bf16x8 xfrag[2][4];
    #pragma unroll
    for (int i = 0; i < 2; ++i) {
        int r = rowBase + i * 16 + l16;
        if (r >= M) r = M - 1;
        #pragma unroll
        for (int kb = 0; kb < 4; ++kb)
            xfrag[i][kb] = *(const bf16x8*)(A + (size_t)r * D + kb * 32 + quad * 8);
    }

    const float* biases[4] = {bq, bk, bv, bs};

    for (int cb = 0; cb < 4; ++cb) {
        const __hip_bfloat16* Wblk = Wt + (size_t)cb * 128 * 128;
        f32x4 acc[2][4];
        #pragma unroll
        for (int i = 0; i < 2; i++)
            #pragma unroll
            for (int jt = 0; jt < 4; jt++) acc[i][jt] = (f32x4){0.f, 0.f, 0.f, 0.f};

        #pragma unroll
        for (int kb = 0; kb < 4; ++kb) {
            const int k0 = kb * 32 + quad * 8;
            #pragma unroll
            for (int jt = 0; jt < 4; ++jt) {
                int c = wc * 64 + jt * 16 + l16;
                bf16x8 wfrag = *(const bf16x8*)(Wblk + (size_t)c * D + k0);
                acc[0][jt] = __builtin_amdgcn_mfma_f32_16x16x32_bf16(wfrag, xfrag[0][kb], acc[0][jt], 0, 0, 0);
                acc[1][jt] = __builtin_amdgcn_mfma_f32_16x16x32_bf16(wfrag, xfrag[1][kb], acc[1][jt], 0, 0, 0);
            }
        }

        // ---- pack acc -> LDS (k goes to bufA, v to bufB, q/skip to bufA)
        __hip_bfloat16* dst = (cb == 2) ? bufB : bufA;
        const float* bias = biases[cb];
        #pragma unroll
        for (int jt = 0; jt < 4; ++jt) {
            int c0 = wc * 64 + jt * 16 + quad * 4;     // 4 consecutive cols
            float4 bb = *(const float4*)(bias + c0);
            #pragma unroll
            for (int i = 0; i < 2; ++i) {
                int lrow = wr * 32 + i * 16 + l16;     // local row 0..63
                f32x4 vv = acc[i][jt];
                __hip_bfloat162 h0 = pack2(vv[0] + bb.x, vv[1] + bb.y);
                __hip_bfloat162 h1 = pack2(vv[2] + bb.z, vv[3] + bb.w);
                float2 st; st.x = *(float*)&h0; st.y = *(float*)&h1;
                *(float2*)(&dst[lrow * TSTR + c0]) = st;   // 8 B, aligned
            }
        }

        if (cb == 1) continue;      // k staged; wait for v before writing kv

        __syncthreads();

        if (cb == 0 || cb == 3) {
            // copy 64x128 bf16 tile -> global, 16 B/lane coalesced
            __hip_bfloat16* gout = (cb == 0) ? qb : skipb;
            #pragma unroll
            for (int it = 0; it < 4; ++it) {
                int lrow = it * 16 + (tid >> 4);
                int grow = blk0 + lrow;
                if (grow < M) {
                    float4 vv = *(const float4*)(&bufA[lrow * TSTR + (tid & 15) * 8]);
                    *(float4*)(gout + (size_t)grow * D + (tid & 15) * 8) = vv;
                }
            }
        } else {
            // cb==2: interleave k (bufA) + v (bufB) -> kv[M,256]:
            // pair p -> [k2p, k2p+1, v2p, v2p+1] at offset 4p
            #pragma unroll
            for (int it = 0; it < 8; ++it) {
                int lrow = it * 8 + (tid >> 5);
                int grow = blk0 + lrow;
                int g = tid & 31;                      // covers k/v cols 4g..4g+3
                if (grow < M) {
                    float2 kk = *(const float2*)(&bufA[lrow * TSTR + g * 4]);
                    float2 vv = *(const float2*)(&bufB[lrow * TSTR + g * 4]);
                    float4 o; o.x = kk.x; o.y = vv.x; o.z = kk.y; o.w = vv.y;
                    *(float4*)(kv + (size_t)grow * 256 + g * 8) = o;
                }
            }
        }
        __syncthreads();            // protect bufA reuse by next phase
    }
}

// ---------------------------------------------------------------------------
// One wave per dst node, online softmax. Lane l holds dims {2l,2l+1};
// head = l>>3, dot reduced over 8 lanes. One dwordx2 kv load per edge.
__device__ inline void store_pair(float* base, int idx, float o0, float o1) {
    ((float2*)base)[idx] = make_float2(o0, o1);
}
__device__ inline void store_pair(__hip_bfloat16* base, int idx, float o0, float o1) {
    ((__hip_bfloat162*)base)[idx] = pack2(o0, o1);
}

template <typename OutT>
__global__ __launch_bounds__(256) void attn_agg(
    const __hip_bfloat16* __restrict__ qb, const __hip_bfloat16* __restrict__ kv,
    const int* __restrict__ row_ptr, const int* __restrict__ srcs,
    const __hip_bfloat16* __restrict__ skip, const float* __restrict__ resid,
    const float* __restrict__ a_ptr, OutT* __restrict__ out, int Nn) {
    int n = blockIdx.x * 4 + (threadIdx.x >> 6);
    if (n >= Nn) return;
    int lane = threadIdx.x & 63;
    const float a = a_ptr[0];

    __hip_bfloat162 qp = ((const __hip_bfloat162*)(qb + (size_t)n * D))[lane];
    float qx = __bfloat162float(qp.x), qy = __bfloat162float(qp.y);
    float m = -INFINITY, s = 0.f, a0 = 0.f, a1 = 0.f;

    int beg = __builtin_amdgcn_readfirstlane(row_ptr[n]);
    int end = __builtin_amdgcn_readfirstlane(row_ptr[n + 1]);
    const float2* kvp = (const float2*)kv;

    int j = beg;
    for (; j + 8 <= end; j += 8) {
        float2 f[8];
        float sc[8];
        #pragma unroll
        for (int i = 0; i < 8; ++i) {
            int src = srcs[j + i];
            f[i] = kvp[(size_t)src * 64 + lane];
        }
        #pragma unroll
        for (int i = 0; i < 8; ++i) {
            __hip_bfloat162 kp = *(__hip_bfloat162*)&f[i].x;
            float p = qx * __bfloat162float(kp.x) + qy * __bfloat162float(kp.y);
            p += __shfl_xor(p, 1);
            p += __shfl_xor(p, 2);
            p += __shfl_xor(p, 4);
            sc[i] = p * SCALE;
        }
        float nm = m;
        #pragma unroll
        for (int i = 0; i < 8; ++i) nm = fmaxf(nm, sc[i]);
        float corr = __expf(m - nm);
        a0 *= corr; a1 *= corr; s *= corr;
        #pragma unroll
        for (int i = 0; i < 8; ++i) {
            float wgt = __expf(sc[i] - nm);
            __hip_bfloat162 vp = *(__hip_bfloat162*)&f[i].y;
            a0 += wgt * __bfloat162float(vp.x);
            a1 += wgt * __bfloat162float(vp.y);
            s += wgt;
        }
        m = nm;
    }
    for (; j < end; j += 4) {
        float2 f[4];
        float sc[4];
        #pragma unroll
        for (int i = 0; i < 4; ++i) {
            int jj = j + i; if (jj > end - 1) jj = end - 1;
            int src = srcs[jj];
            f[i] = kvp[(size_t)src * 64 + lane];
        }
        #pragma unroll
        for (int i = 0; i < 4; ++i) {
            __hip_bfloat162 kp = *(__hip_bfloat162*)&f[i].x;
            float p = qx * __bfloat162float(kp.x) + qy * __bfloat162float(kp.y);
            p += __shfl_xor(p, 1);
            p += __shfl_xor(p, 2);
            p += __shfl_xor(p, 4);
            sc[i] = (j + i < end) ? p * SCALE : -INFINITY;
        }
        float nm = m;
        #pragma unroll
        for (int i = 0; i < 4; ++i) nm = fmaxf(nm, sc[i]);
        float corr = __expf(m - nm);
        a0 *= corr; a1 *= corr; s *= corr;
        #pragma unroll
        for (int i = 0; i < 4; ++i) {
            float wgt = __expf(sc[i] - nm);
            __hip_bfloat162 vp = *(__hip_bfloat162*)&f[i].y;
            a0 += wgt * __bfloat162float(vp.x);
            a1 += wgt * __bfloat162float(vp.y);
            s += wgt;
        }
        m = nm;
    }

    float inv = (end > beg) ? 1.f / s : 0.f;
    __hip_bfloat162 skp = ((const __hip_bfloat162*)(skip + (size_t)n * D))[lane];
    float o0 = a0 * inv + __bfloat162float(skp.x);
    float o1 = a1 * inv + __bfloat162float(skp.y);
    if (resid) {
        float2 rs = ((const float2*)(resid + (size_t)n * D))[lane];
        o0 += rs.x; o1 += rs.y;
    }
    o0 = (o0 >= 0.f) ? o0 : a * o0;
    o1 = (o1 >= 0.f) ? o1 : a * o1;
    store_pair(out, n * (D / 2) + lane, o0, o1);
}

// ---------------------------------------------------------------------------
extern "C" void kernel_launch(void* const* d_in, const int* in_sizes, int n_in,
                              void* d_out, int out_size, void* d_ws, size_t ws_size,
                              hipStream_t stream) {
    const float* x  = (const float*)d_in[0];
    const int*   ei = (const int*)d_in[1];
    const float* a  = (const float*)d_in[2];
    const float* Wq1 = (const float*)d_in[3];  const float* bq1 = (const float*)d_in[4];
    const float* Wk1 = (const float*)d_in[5];  const float* bk1 = (const float*)d_in[6];
    const float* Wv1 = (const float*)d_in[7];  const float* bv1 = (const float*)d_in[8];
    const float* Ws1 = (const float*)d_in[9];  const float* bs1 = (const float*)d_in[10];
    const float* Wq2 = (const float*)d_in[11]; const float* bq2 = (const float*)d_in[12];
    const float* Wk2 = (const float*)d_in[13]; const float* bk2 = (const float*)d_in[14];
    const float* Wv2 = (const float*)d_in[15]; const float* bv2 = (const float*)d_in[16];
    const float* Ws2 = (const float*)d_in[17]; const float* bs2 = (const float*)d_in[18];

    const int N = in_sizes[0] / D;        // 100000
    const int E = in_sizes[1] / 2;        // 1000000
    const size_t NF = (size_t)N * D;

    char* wp = (char*)d_ws;
    __hip_bfloat16* xb    = (__hip_bfloat16*)wp; wp += NF * 2;
    __hip_bfloat16* h1b   = (__hip_bfloat16*)wp; wp += NF * 2;
    __hip_bfloat16* qb    = (__hip_bfloat16*)wp; wp += NF * 2;
    __hip_bfloat16* kv    = (__hip_bfloat16*)wp; wp += NF * 4;   // [N,256] pair-interleaved
    __hip_bfloat16* skipb = (__hip_bfloat16*)wp; wp += NF * 2;
    __hip_bfloat16* WtP   = (__hip_bfloat16*)wp; wp += 2 * 512 * 128 * 2;
    int* flag    = (int*)wp;  wp += 64;
    int* deg     = (int*)wp;  wp += (size_t)N * 4;
    int* row_ptr = (int*)wp;  wp += (size_t)(N + 64) * 4;
    int* cursor  = (int*)wp;  wp += (size_t)N * 4;
    int* bsum    = (int*)wp;  wp += 1024 * 4;
    int* boff    = (int*)wp;  wp += 1024 * 4;
    int* srcs    = (int*)wp;  wp += (size_t)E * 4;
    float* out   = (float*)d_out;

    const int TB = 256;
    int gN = (N + TB - 1) / TB;
    int gE = (E + TB - 1) / TB;
    int NB = (N + 1023) / 1024;
    int gGemm = (N + 63) / 64;
    int gAttn = (N + 3) / 4;
    int gCvt  = ((int)(NF / 4) + TB - 1) / TB;

    // ---- CSR build ----
    hipLaunchKernelGGL(detect_i64, dim3(1), dim3(1024), 0, stream, ei, flag);
    hipLaunchKernelGGL(zero_ints, dim3(gN), dim3(TB), 0, stream, deg, N);
    hipLaunchKernelGGL(count_deg, dim3(gE), dim3(TB), 0, stream, ei, E, flag, deg);
    hipLaunchKernelGGL(scan_blocks, dim3(NB), dim3(1024), 0, stream, deg, row_ptr, bsum, N);
    hipLaunchKernelGGL(scan_bsum, dim3(1), dim3(1024), 0, stream, bsum, boff, NB, row_ptr, N);
    hipLaunchKernelGGL(add_offsets, dim3(gN), dim3(TB), 0, stream, row_ptr, cursor, boff, N);
    hipLaunchKernelGGL(scatter_edges, dim3(gE), dim3(TB), 0, stream, ei, E, flag, cursor, srcs);

    // ---- weight pack + input convert ----
    PackArgs pa;
    pa.w[0] = Wq1; pa.w[1] = Wk1; pa.w[2] = Wv1; pa.w[3] = Ws1;
    pa.w[4] = Wq2; pa.w[5] = Wk2; pa.w[6] = Wv2; pa.w[7] = Ws2;
    hipLaunchKernelGGL(pack_w, dim3(8), dim3(TB), 0, stream, pa, WtP);
    hipLaunchKernelGGL(f32_to_bf16, dim3(gCvt), dim3(TB), 0, stream, x, xb, (int)(NF / 4));

    // ---- layer 1 ----
    hipLaunchKernelGGL(gemm_mfma, dim3(gGemm), dim3(TB), 0, stream,
                       xb, WtP, bq1, bk1, bv1, bs1, qb, kv, skipb, N);
    hipLaunchKernelGGL(attn_agg<__hip_bfloat16>, dim3(gAttn), dim3(TB), 0, stream,
                       qb, kv, row_ptr, srcs, skipb, (const float*)nullptr, a, h1b, N);

    // ---- layer 2 ----
    hipLaunchKernelGGL(gemm_mfma, dim3(gGemm), dim3(TB), 0, stream,
                       h1b, WtP + 512 * 128, bq2, bk2, bv2, bs2, qb, kv, skipb, N);
    hipLaunchKernelGGL(attn_agg<float>, dim3(gAttn), dim3(TB), 0, stream,
                       qb, kv, row_ptr, srcs, skipb, x, a, out, N);
}

// Round 6
// 590.906 us; speedup vs baseline: 1.0435x; 1.0116x over previous
//
#include <hip/hip_runtime.h>
#include <hip/hip_bf16.h>
#include <math.h>

#define D 128
#define SCALE 0.25f
#define NEG_BIG (-1e30f)

typedef __attribute__((ext_vector_type(8))) short bf16x8;
typedef __attribute__((ext_vector_type(4))) float f32x4;

__device__ inline __hip_bfloat162 pack2(float a, float b) {
    __hip_bfloat162 h;
    h.x = __float2bfloat16(a);
    h.y = __float2bfloat16(b);
    return h;
}

// ---------------------------------------------------------------------------
// prep: blocks [0,8) pack weights; block 8 detects edge dtype; blocks
// [9, 9+gN) zero deg; remaining blocks convert x -> bf16. All independent.
struct PackArgs { const float* w[8]; };

__global__ __launch_bounds__(256) void prep(
    PackArgs pa, __hip_bfloat16* __restrict__ WtP,
    const float* __restrict__ x, __hip_bfloat16* __restrict__ xb, int n4,
    const int* __restrict__ ei, int* __restrict__ flag,
    int* __restrict__ deg, int Nn, int gN)
{
    int b = blockIdx.x;
    int tid = threadIdx.x;
    if (b < 8) {
        const float* W = pa.w[b];
        __hip_bfloat16* dst = WtP + (size_t)b * 128 * 128;
        for (int idx = tid; idx < 128 * 128; idx += 256) {
            int c = idx & 127, k = idx >> 7;
            dst[(size_t)c * 128 + k] = __float2bfloat16(W[(size_t)k * 128 + c]);
        }
    } else if (b == 8) {
        __shared__ int cnt;
        if (tid == 0) cnt = 0;
        __syncthreads();
        int v = ei[2 * tid + 1];          // odd words: int64 high halves == 0
        if (v != 0) atomicAdd(&cnt, 1);
        __syncthreads();
        if (tid == 0) flag[0] = (cnt == 0) ? 1 : 0;
    } else if (b < 9 + gN) {
        int i = (b - 9) * 256 + tid;
        if (i < Nn) deg[i] = 0;
    } else {
        int i = (b - 9 - gN) * 256 + tid;
        if (i < n4) {
            float4 v = ((const float4*)x)[i];
            ((__hip_bfloat162*)xb)[2 * i]     = pack2(v.x, v.y);
            ((__hip_bfloat162*)xb)[2 * i + 1] = pack2(v.z, v.w);
        }
    }
}

__global__ void count_deg(const int* __restrict__ ei, int E,
                          const int* __restrict__ flag, int* __restrict__ deg) {
    int e = blockIdx.x * blockDim.x + threadIdx.x;
    if (e >= E) return;
    int is64 = flag[0];
    int d = is64 ? ei[2 * E + 2 * e] : ei[E + e];
    atomicAdd(&deg[d], 1);
}

__global__ __launch_bounds__(1024) void scan_blocks(const int* __restrict__ deg,
                                                    int* __restrict__ row_ptr,
                                                    int* __restrict__ bsum, int Nn) {
    __shared__ int buf[1024];
    int tid = threadIdx.x;
    int i = blockIdx.x * 1024 + tid;
    int v = (i < Nn) ? deg[i] : 0;
    buf[tid] = v;
    __syncthreads();
    for (int off = 1; off < 1024; off <<= 1) {
        int t = (tid >= off) ? buf[tid - off] : 0;
        __syncthreads();
        buf[tid] += t;
        __syncthreads();
    }
    if (i < Nn) row_ptr[i] = buf[tid] - v;
    if (tid == 1023) bsum[blockIdx.x] = buf[1023];
}

__global__ __launch_bounds__(1024) void scan_bsum(int* __restrict__ bsum,
                                                  int* __restrict__ boff,
                                                  int NB, int* __restrict__ row_ptr, int Nn) {
    __shared__ int buf[1024];
    int tid = threadIdx.x;
    int v = (tid < NB) ? bsum[tid] : 0;
    buf[tid] = v;
    __syncthreads();
    for (int off = 1; off < 1024; off <<= 1) {
        int t = (tid >= off) ? buf[tid - off] : 0;
        __syncthreads();
        buf[tid] += t;
        __syncthreads();
    }
    if (tid < NB) boff[tid] = buf[tid] - v;
    if (tid == 0) row_ptr[Nn] = buf[NB - 1];
}

__global__ void add_offsets(int* __restrict__ row_ptr, int* __restrict__ cursor,
                            const int* __restrict__ boff, int Nn) {
    int i = blockIdx.x * blockDim.x + threadIdx.x;
    if (i < Nn) {
        int r = row_ptr[i] + boff[i >> 10];
        row_ptr[i] = r;
        cursor[i] = r;
    }
}

__global__ void scatter_edges(const int* __restrict__ ei, int E,
                              const int* __restrict__ flag,
                              int* __restrict__ cursor, int* __restrict__ srcs) {
    int e = blockIdx.x * blockDim.x + threadIdx.x;
    if (e >= E) return;
    int is64 = flag[0];
    int s = is64 ? ei[2 * e]         : ei[e];
    int d = is64 ? ei[2 * E + 2 * e] : ei[E + e];
    int pos = atomicAdd(&cursor[d], 1);
    srcs[pos] = s;
}

// ---------------------------------------------------------------------------
// Fused 4-way GEMM, swapped-operand MFMA, LDS-staged coalesced epilogue.
// kv layout: row n = 32 groups of 8: group g = [k4g..k4g+3, v4g..v4g+3].
#define TSTR 136

__global__ __launch_bounds__(256) void gemm_mfma(
    const __hip_bfloat16* __restrict__ A,   // [M,128]
    const __hip_bfloat16* __restrict__ Wt,  // [512,128] (col,k)
    const float* __restrict__ bq, const float* __restrict__ bk,
    const float* __restrict__ bv, const float* __restrict__ bs,
    __hip_bfloat16* __restrict__ qb, __hip_bfloat16* __restrict__ kv,
    __hip_bfloat16* __restrict__ skipb, int M)
{
    __shared__ __hip_bfloat16 bufA[64 * TSTR];
    __shared__ __hip_bfloat16 bufB[64 * TSTR];

    const int tid = threadIdx.x;
    const int w = tid >> 6, lane = tid & 63;
    const int wr = w >> 1, wc = w & 1;
    const int blk0 = blockIdx.x * 64;
    const int rowBase = blk0 + wr * 32;
    const int l16 = lane & 15;
    const int quad = lane >> 4;

    bf16x8 xfrag[2][4];
    #pragma unroll
    for (int i = 0; i < 2; ++i) {
        int r = rowBase + i * 16 + l16;
        if (r >= M) r = M - 1;
        #pragma unroll
        for (int kb = 0; kb < 4; ++kb)
            xfrag[i][kb] = *(const bf16x8*)(A + (size_t)r * D + kb * 32 + quad * 8);
    }

    const float* biases[4] = {bq, bk, bv, bs};

    for (int cb = 0; cb < 4; ++cb) {
        const __hip_bfloat16* Wblk = Wt + (size_t)cb * 128 * 128;
        f32x4 acc[2][4];
        #pragma unroll
        for (int i = 0; i < 2; i++)
            #pragma unroll
            for (int jt = 0; jt < 4; jt++) acc[i][jt] = (f32x4){0.f, 0.f, 0.f, 0.f};

        #pragma unroll
        for (int kb = 0; kb < 4; ++kb) {
            const int k0 = kb * 32 + quad * 8;
            #pragma unroll
            for (int jt = 0; jt < 4; ++jt) {
                int c = wc * 64 + jt * 16 + l16;
                bf16x8 wfrag = *(const bf16x8*)(Wblk + (size_t)c * D + k0);
                acc[0][jt] = __builtin_amdgcn_mfma_f32_16x16x32_bf16(wfrag, xfrag[0][kb], acc[0][jt], 0, 0, 0);
                acc[1][jt] = __builtin_amdgcn_mfma_f32_16x16x32_bf16(wfrag, xfrag[1][kb], acc[1][jt], 0, 0, 0);
            }
        }

        __hip_bfloat16* dst = (cb == 2) ? bufB : bufA;
        const float* bias = biases[cb];
        #pragma unroll
        for (int jt = 0; jt < 4; ++jt) {
            int c0 = wc * 64 + jt * 16 + quad * 4;
            float4 bb = *(const float4*)(bias + c0);
            #pragma unroll
            for (int i = 0; i < 2; ++i) {
                int lrow = wr * 32 + i * 16 + l16;
                f32x4 vv = acc[i][jt];
                __hip_bfloat162 h0 = pack2(vv[0] + bb.x, vv[1] + bb.y);
                __hip_bfloat162 h1 = pack2(vv[2] + bb.z, vv[3] + bb.w);
                float2 st; st.x = *(float*)&h0; st.y = *(float*)&h1;
                *(float2*)(&dst[lrow * TSTR + c0]) = st;
            }
        }

        if (cb == 1) continue;

        __syncthreads();

        if (cb == 0 || cb == 3) {
            __hip_bfloat16* gout = (cb == 0) ? qb : skipb;
            #pragma unroll
            for (int it = 0; it < 4; ++it) {
                int lrow = it * 16 + (tid >> 4);
                int grow = blk0 + lrow;
                if (grow < M) {
                    float4 vv = *(const float4*)(&bufA[lrow * TSTR + (tid & 15) * 8]);
                    *(float4*)(gout + (size_t)grow * D + (tid & 15) * 8) = vv;
                }
            }
        } else {
            // interleave k (bufA) + v (bufB): group g -> [k4g..4g+3, v4g..4g+3]
            #pragma unroll
            for (int it = 0; it < 8; ++it) {
                int lrow = it * 8 + (tid >> 5);
                int grow = blk0 + lrow;
                int g = tid & 31;
                if (grow < M) {
                    float2 kk = *(const float2*)(&bufA[lrow * TSTR + g * 4]);
                    float2 vv = *(const float2*)(&bufB[lrow * TSTR + g * 4]);
                    float4 o; o.x = kk.x; o.y = kk.y; o.z = vv.x; o.w = vv.y;
                    *(float4*)(kv + (size_t)grow * 256 + g * 8) = o;
                }
            }
        }
        __syncthreads();
    }
}

// ---------------------------------------------------------------------------
// attn: 2 nodes per wave (half-waves), lane lh owns dims [4lh,4lh+4).
// Head = 4 lanes -> 2-step shuffle reduce. One dwordx4 kv load per edge-slot.
__device__ inline void store4(float* base, size_t off, float o0, float o1, float o2, float o3) {
    *(float4*)(base + off) = make_float4(o0, o1, o2, o3);
}
__device__ inline void store4(__hip_bfloat16* base, size_t off, float o0, float o1, float o2, float o3) {
    __hip_bfloat162 h0 = pack2(o0, o1), h1 = pack2(o2, o3);
    float2 st; st.x = *(float*)&h0; st.y = *(float*)&h1;
    *(float2*)(base + off) = st;
}

template <typename OutT>
__global__ __launch_bounds__(256) void attn_agg(
    const __hip_bfloat16* __restrict__ qb, const __hip_bfloat16* __restrict__ kv,
    const int* __restrict__ row_ptr, const int* __restrict__ srcs,
    const __hip_bfloat16* __restrict__ skip, const __hip_bfloat16* __restrict__ residb,
    const float* __restrict__ a_ptr, OutT* __restrict__ out, int Nn) {
    int tid = threadIdx.x;
    int lane = tid & 63;
    int half = lane >> 5;
    int lh = lane & 31;
    int n = blockIdx.x * 8 + (tid >> 6) * 2 + half;
    bool valid = (n < Nn);
    int nc = valid ? n : (Nn - 1);
    const float a = a_ptr[0];

    float2 qraw = *(const float2*)(qb + (size_t)nc * D + 4 * lh);
    __hip_bfloat162 q01 = *(__hip_bfloat162*)&qraw.x;
    __hip_bfloat162 q23 = *(__hip_bfloat162*)&qraw.y;
    float q0 = __bfloat162float(q01.x) * SCALE, q1 = __bfloat162float(q01.y) * SCALE;
    float q2 = __bfloat162float(q23.x) * SCALE, q3 = __bfloat162float(q23.y) * SCALE;

    float m = NEG_BIG, s = 0.f, A0 = 0.f, A1 = 0.f, A2 = 0.f, A3 = 0.f;

    int beg = row_ptr[nc];
    int end = valid ? row_ptr[nc + 1] : beg;
    int cnt = end - beg;
    int cmax = max(cnt, __shfl_xor(cnt, 32));

    const float4* kvp4 = (const float4*)kv;   // 32 float4 per row

    for (int t = 0; t < cmax; t += 4) {
        float4 f[4];
        float sc[4];
        #pragma unroll
        for (int i = 0; i < 4; ++i) {
            int j = beg + t + i;
            int jj = (j < end) ? j : (end - 1);
            if (jj < 0) jj = 0;
            int src = srcs[jj];
            f[i] = kvp4[(size_t)src * 32 + lh];
        }
        #pragma unroll
        for (int i = 0; i < 4; ++i) {
            __hip_bfloat162 k01 = *(__hip_bfloat162*)&f[i].x;
            __hip_bfloat162 k23 = *(__hip_bfloat162*)&f[i].y;
            float p = q0 * __bfloat162float(k01.x) + q1 * __bfloat162float(k01.y)
                    + q2 * __bfloat162float(k23.x) + q3 * __bfloat162float(k23.y);
            p += __shfl_xor(p, 1);
            p += __shfl_xor(p, 2);
            sc[i] = (t + i < cnt) ? p : NEG_BIG;
        }
        float nm = m;
        #pragma unroll
        for (int i = 0; i < 4; ++i) nm = fmaxf(nm, sc[i]);
        float corr = __expf(m - nm);
        A0 *= corr; A1 *= corr; A2 *= corr; A3 *= corr; s *= corr;
        #pragma unroll
        for (int i = 0; i < 4; ++i) {
            float wgt = __expf(sc[i] - nm);
            __hip_bfloat162 v01 = *(__hip_bfloat162*)&f[i].z;
            __hip_bfloat162 v23 = *(__hip_bfloat162*)&f[i].w;
            A0 += wgt * __bfloat162float(v01.x);
            A1 += wgt * __bfloat162float(v01.y);
            A2 += wgt * __bfloat162float(v23.x);
            A3 += wgt * __bfloat162float(v23.y);
            s += wgt;
        }
        m = nm;
    }

    if (!valid) return;
    float inv = (cnt > 0) ? 1.f / s : 0.f;
    float2 skr = *(const float2*)(skip + (size_t)n * D + 4 * lh);
    __hip_bfloat162 s01 = *(__hip_bfloat162*)&skr.x;
    __hip_bfloat162 s23 = *(__hip_bfloat162*)&skr.y;
    float o0 = A0 * inv + __bfloat162float(s01.x);
    float o1 = A1 * inv + __bfloat162float(s01.y);
    float o2 = A2 * inv + __bfloat162float(s23.x);
    float o3 = A3 * inv + __bfloat162float(s23.y);
    if (residb) {
        float2 rr = *(const float2*)(residb + (size_t)n * D + 4 * lh);
        __hip_bfloat162 r01 = *(__hip_bfloat162*)&rr.x;
        __hip_bfloat162 r23 = *(__hip_bfloat162*)&rr.y;
        o0 += __bfloat162float(r01.x);
        o1 += __bfloat162float(r01.y);
        o2 += __bfloat162float(r23.x);
        o3 += __bfloat162float(r23.y);
    }
    o0 = (o0 >= 0.f) ? o0 : a * o0;
    o1 = (o1 >= 0.f) ? o1 : a * o1;
    o2 = (o2 >= 0.f) ? o2 : a * o2;
    o3 = (o3 >= 0.f) ? o3 : a * o3;
    store4(out, (size_t)n * D + 4 * lh, o0, o1, o2, o3);
}

// ---------------------------------------------------------------------------
extern "C" void kernel_launch(void* const* d_in, const int* in_sizes, int n_in,
                              void* d_out, int out_size, void* d_ws, size_t ws_size,
                              hipStream_t stream) {
    const float* x  = (const float*)d_in[0];
    const int*   ei = (const int*)d_in[1];
    const float* a  = (const float*)d_in[2];
    const float* Wq1 = (const float*)d_in[3];  const float* bq1 = (const float*)d_in[4];
    const float* Wk1 = (const float*)d_in[5];  const float* bk1 = (const float*)d_in[6];
    const float* Wv1 = (const float*)d_in[7];  const float* bv1 = (const float*)d_in[8];
    const float* Ws1 = (const float*)d_in[9];  const float* bs1 = (const float*)d_in[10];
    const float* Wq2 = (const float*)d_in[11]; const float* bq2 = (const float*)d_in[12];
    const float* Wk2 = (const float*)d_in[13]; const float* bk2 = (const float*)d_in[14];
    const float* Wv2 = (const float*)d_in[15]; const float* bv2 = (const float*)d_in[16];
    const float* Ws2 = (const float*)d_in[17]; const float* bs2 = (const float*)d_in[18];

    const int N = in_sizes[0] / D;        // 100000
    const int E = in_sizes[1] / 2;        // 1000000
    const size_t NF = (size_t)N * D;

    char* wp = (char*)d_ws;
    __hip_bfloat16* xb    = (__hip_bfloat16*)wp; wp += NF * 2;
    __hip_bfloat16* h1b   = (__hip_bfloat16*)wp; wp += NF * 2;
    __hip_bfloat16* qb    = (__hip_bfloat16*)wp; wp += NF * 2;
    __hip_bfloat16* kv    = (__hip_bfloat16*)wp; wp += NF * 4;
    __hip_bfloat16* skipb = (__hip_bfloat16*)wp; wp += NF * 2;
    __hip_bfloat16* WtP   = (__hip_bfloat16*)wp; wp += 2 * 512 * 128 * 2;
    int* flag    = (int*)wp;  wp += 64;
    int* deg     = (int*)wp;  wp += (size_t)N * 4;
    int* row_ptr = (int*)wp;  wp += (size_t)(N + 64) * 4;
    int* cursor  = (int*)wp;  wp += (size_t)N * 4;
    int* bsum    = (int*)wp;  wp += 1024 * 4;
    int* boff    = (int*)wp;  wp += 1024 * 4;
    int* srcs    = (int*)wp;  wp += (size_t)E * 4;
    float* out   = (float*)d_out;

    const int TB = 256;
    int gN = (N + TB - 1) / TB;
    int gE = (E + TB - 1) / TB;
    int NB = (N + 1023) / 1024;
    int gGemm = (N + 63) / 64;
    int gAttn = (N + 7) / 8;
    int n4 = (int)(NF / 4);
    int gCvt = (n4 + TB - 1) / TB;

    PackArgs pa;
    pa.w[0] = Wq1; pa.w[1] = Wk1; pa.w[2] = Wv1; pa.w[3] = Ws1;
    pa.w[4] = Wq2; pa.w[5] = Wk2; pa.w[6] = Wv2; pa.w[7] = Ws2;

    // ---- fused prep: pack_w | detect | zero deg | x->bf16 ----
    hipLaunchKernelGGL(prep, dim3(9 + gN + gCvt), dim3(TB), 0, stream,
                       pa, WtP, x, xb, n4, ei, flag, deg, N, gN);

    // ---- CSR build ----
    hipLaunchKernelGGL(count_deg, dim3(gE), dim3(TB), 0, stream, ei, E, flag, deg);
    hipLaunchKernelGGL(scan_blocks, dim3(NB), dim3(1024), 0, stream, deg, row_ptr, bsum, N);
    hipLaunchKernelGGL(scan_bsum, dim3(1), dim3(1024), 0, stream, bsum, boff, NB, row_ptr, N);
    hipLaunchKernelGGL(add_offsets, dim3(gN), dim3(TB), 0, stream, row_ptr, cursor, boff, N);
    hipLaunchKernelGGL(scatter_edges, dim3(gE), dim3(TB), 0, stream, ei, E, flag, cursor, srcs);

    // ---- layer 1 ----
    hipLaunchKernelGGL(gemm_mfma, dim3(gGemm), dim3(TB), 0, stream,
                       xb, WtP, bq1, bk1, bv1, bs1, qb, kv, skipb, N);
    hipLaunchKernelGGL(attn_agg<__hip_bfloat16>, dim3(gAttn), dim3(TB), 0, stream,
                       qb, kv, row_ptr, srcs, skipb, (const __hip_bfloat16*)nullptr, a, h1b, N);

    // ---- layer 2 ----
    hipLaunchKernelGGL(gemm_mfma, dim3(gGemm), dim3(TB), 0, stream,
                       h1b, WtP + 512 * 128, bq2, bk2, bv2, bs2, qb, kv, skipb, N);
    hipLaunchKernelGGL(attn_agg<float>, dim3(gAttn), dim3(TB), 0, stream,
                       qb, kv, row_ptr, srcs, skipb, xb, a, out, N);
}

// Round 7
// 567.748 us; speedup vs baseline: 1.0861x; 1.0408x over previous
//
#include <hip/hip_runtime.h>
#include <hip/hip_bf16.h>
#include <math.h>

#define D 128
#define SCALE 0.25f
#define NEG_BIG (-1e30f)

typedef __attribute__((ext_vector_type(8))) short bf16x8;
typedef __attribute__((ext_vector_type(4))) float f32x4;

__device__ inline __hip_bfloat162 pack2(float a, float b) {
    __hip_bfloat162 h;
    h.x = __float2bfloat16(a);
    h.y = __float2bfloat16(b);
    return h;
}

// int64 vs int32 edge_index: int64 little-endian high words (odd int32s) are
// all zero for ids < 2^31; int32 layout puts random node ids there.
// Per-wave ballot over 64 samples — no cross-kernel dependency.
__device__ inline int detect_is64(const int* __restrict__ ei) {
    int lane = threadIdx.x & 63;
    int v = ei[2 * lane + 1];
    unsigned long long b = __ballot(v != 0);
    return b == 0ULL;
}

// ---------------------------------------------------------------------------
// prep: blocks [0,gE) count degrees (1e6 atomics — longest pole, first);
// [gE,gE+8) pack weights; rest convert x -> bf16. deg pre-zeroed by memset.
struct PackArgs { const float* w[8]; };

__global__ __launch_bounds__(256) void prep(
    PackArgs pa, __hip_bfloat16* __restrict__ WtP,
    const float* __restrict__ x, __hip_bfloat16* __restrict__ xb, int n4,
    const int* __restrict__ ei, int E, int* __restrict__ deg, int gE)
{
    int b = blockIdx.x;
    int tid = threadIdx.x;
    if (b < gE) {
        int is64 = detect_is64(ei);
        int e = b * 256 + tid;
        if (e < E) {
            int d = is64 ? ei[2 * E + 2 * e] : ei[E + e];
            atomicAdd(&deg[d], 1);
        }
    } else if (b < gE + 8) {
        int w = b - gE;
        const float* W = pa.w[w];
        __hip_bfloat16* dst = WtP + (size_t)w * 128 * 128;
        for (int idx = tid; idx < 128 * 128; idx += 256) {
            int c = idx & 127, k = idx >> 7;
            dst[(size_t)c * 128 + k] = __float2bfloat16(W[(size_t)k * 128 + c]);
        }
    } else {
        int i = (b - gE - 8) * 256 + tid;
        if (i < n4) {
            float4 v = ((const float4*)x)[i];
            ((__hip_bfloat162*)xb)[2 * i]     = pack2(v.x, v.y);
            ((__hip_bfloat162*)xb)[2 * i + 1] = pack2(v.z, v.w);
        }
    }
}

__global__ __launch_bounds__(1024) void scan_blocks(const int* __restrict__ deg,
                                                    int* __restrict__ row_ptr,
                                                    int* __restrict__ bsum, int Nn) {
    __shared__ int buf[1024];
    int tid = threadIdx.x;
    int i = blockIdx.x * 1024 + tid;
    int v = (i < Nn) ? deg[i] : 0;
    buf[tid] = v;
    __syncthreads();
    for (int off = 1; off < 1024; off <<= 1) {
        int t = (tid >= off) ? buf[tid - off] : 0;
        __syncthreads();
        buf[tid] += t;
        __syncthreads();
    }
    if (i < Nn) row_ptr[i] = buf[tid] - v;
    if (tid == 1023) bsum[blockIdx.x] = buf[1023];
}

__global__ __launch_bounds__(1024) void scan_bsum(int* __restrict__ bsum,
                                                  int* __restrict__ boff,
                                                  int NB, int* __restrict__ row_ptr, int Nn) {
    __shared__ int buf[1024];
    int tid = threadIdx.x;
    int v = (tid < NB) ? bsum[tid] : 0;
    buf[tid] = v;
    __syncthreads();
    for (int off = 1; off < 1024; off <<= 1) {
        int t = (tid >= off) ? buf[tid - off] : 0;
        __syncthreads();
        buf[tid] += t;
        __syncthreads();
    }
    if (tid < NB) boff[tid] = buf[tid] - v;
    if (tid == 0) row_ptr[Nn] = buf[NB - 1];
}

__global__ void add_offsets(int* __restrict__ row_ptr, int* __restrict__ cursor,
                            const int* __restrict__ boff, int Nn) {
    int i = blockIdx.x * blockDim.x + threadIdx.x;
    if (i < Nn) {
        int r = row_ptr[i] + boff[i >> 10];
        row_ptr[i] = r;
        cursor[i] = r;
    }
}

// ---------------------------------------------------------------------------
// GEMM body (shared by standalone kernel and the merged gemm+scatter kernel).
// Swapped-operand MFMA; LDS-staged coalesced epilogue.
// kv layout: row n = 32 groups of 8: group g = [k4g..k4g+3, v4g..v4g+3].
#define TSTR 136

__device__ __forceinline__ void gemm_body(
    int bx, __hip_bfloat16* bufA, __hip_bfloat16* bufB,
    const __hip_bfloat16* __restrict__ A, const __hip_bfloat16* __restrict__ Wt,
    const float* __restrict__ bq, const float* __restrict__ bk,
    const float* __restrict__ bv, const float* __restrict__ bs,
    __hip_bfloat16* __restrict__ qb, __hip_bfloat16* __restrict__ kv,
    __hip_bfloat16* __restrict__ skipb, int M)
{
    const int tid = threadIdx.x;
    const int w = tid >> 6, lane = tid & 63;
    const int wr = w >> 1, wc = w & 1;
    const int blk0 = bx * 64;
    const int rowBase = blk0 + wr * 32;
    const int l16 = lane & 15;
    const int quad = lane >> 4;

    bf16x8 xfrag[2][4];
    #pragma unroll
    for (int i = 0; i < 2; ++i) {
        int r = rowBase + i * 16 + l16;
        if (r >= M) r = M - 1;
        #pragma unroll
        for (int kb = 0; kb < 4; ++kb)
            xfrag[i][kb] = *(const bf16x8*)(A + (size_t)r * D + kb * 32 + quad * 8);
    }

    const float* biases[4] = {bq, bk, bv, bs};

    for (int cb = 0; cb < 4; ++cb) {
        const __hip_bfloat16* Wblk = Wt + (size_t)cb * 128 * 128;
        f32x4 acc[2][4];
        #pragma unroll
        for (int i = 0; i < 2; i++)
            #pragma unroll
            for (int jt = 0; jt < 4; jt++) acc[i][jt] = (f32x4){0.f, 0.f, 0.f, 0.f};

        #pragma unroll
        for (int kb = 0; kb < 4; ++kb) {
            const int k0 = kb * 32 + quad * 8;
            #pragma unroll
            for (int jt = 0; jt < 4; ++jt) {
                int c = wc * 64 + jt * 16 + l16;
                bf16x8 wfrag = *(const bf16x8*)(Wblk + (size_t)c * D + k0);
                acc[0][jt] = __builtin_amdgcn_mfma_f32_16x16x32_bf16(wfrag, xfrag[0][kb], acc[0][jt], 0, 0, 0);
                acc[1][jt] = __builtin_amdgcn_mfma_f32_16x16x32_bf16(wfrag, xfrag[1][kb], acc[1][jt], 0, 0, 0);
            }
        }

        __hip_bfloat16* dst = (cb == 2) ? bufB : bufA;
        const float* bias = biases[cb];
        #pragma unroll
        for (int jt = 0; jt < 4; ++jt) {
            int c0 = wc * 64 + jt * 16 + quad * 4;
            float4 bb = *(const float4*)(bias + c0);
            #pragma unroll
            for (int i = 0; i < 2; ++i) {
                int lrow = wr * 32 + i * 16 + l16;
                f32x4 vv = acc[i][jt];
                __hip_bfloat162 h0 = pack2(vv[0] + bb.x, vv[1] + bb.y);
                __hip_bfloat162 h1 = pack2(vv[2] + bb.z, vv[3] + bb.w);
                float2 st; st.x = *(float*)&h0; st.y = *(float*)&h1;
                *(float2*)(&dst[lrow * TSTR + c0]) = st;
            }
        }

        if (cb == 1) continue;

        __syncthreads();

        if (cb == 0 || cb == 3) {
            __hip_bfloat16* gout = (cb == 0) ? qb : skipb;
            #pragma unroll
            for (int it = 0; it < 4; ++it) {
                int lrow = it * 16 + (tid >> 4);
                int grow = blk0 + lrow;
                if (grow < M) {
                    float4 vv = *(const float4*)(&bufA[lrow * TSTR + (tid & 15) * 8]);
                    *(float4*)(gout + (size_t)grow * D + (tid & 15) * 8) = vv;
                }
            }
        } else {
            #pragma unroll
            for (int it = 0; it < 8; ++it) {
                int lrow = it * 8 + (tid >> 5);
                int grow = blk0 + lrow;
                int g = tid & 31;
                if (grow < M) {
                    float2 kk = *(const float2*)(&bufA[lrow * TSTR + g * 4]);
                    float2 vv = *(const float2*)(&bufB[lrow * TSTR + g * 4]);
                    float4 o; o.x = kk.x; o.y = kk.y; o.z = vv.x; o.w = vv.y;
                    *(float4*)(kv + (size_t)grow * 256 + g * 8) = o;
                }
            }
        }
        __syncthreads();
    }
}

__global__ __launch_bounds__(256) void gemm_mfma(
    const __hip_bfloat16* __restrict__ A, const __hip_bfloat16* __restrict__ Wt,
    const float* __restrict__ bq, const float* __restrict__ bk,
    const float* __restrict__ bv, const float* __restrict__ bs,
    __hip_bfloat16* __restrict__ qb, __hip_bfloat16* __restrict__ kv,
    __hip_bfloat16* __restrict__ skipb, int M)
{
    __shared__ __hip_bfloat16 bufA[64 * TSTR];
    __shared__ __hip_bfloat16 bufB[64 * TSTR];
    gemm_body(blockIdx.x, bufA, bufB, A, Wt, bq, bk, bv, bs, qb, kv, skipb, M);
}

// merged: blocks [0,gE) scatter edges; [gE, gE+gGemm) layer-1 GEMM.
__global__ __launch_bounds__(256) void gemm_scatter(
    const __hip_bfloat16* __restrict__ A, const __hip_bfloat16* __restrict__ Wt,
    const float* __restrict__ bq, const float* __restrict__ bk,
    const float* __restrict__ bv, const float* __restrict__ bs,
    __hip_bfloat16* __restrict__ qb, __hip_bfloat16* __restrict__ kv,
    __hip_bfloat16* __restrict__ skipb, int M,
    const int* __restrict__ ei, int E,
    int* __restrict__ cursor, int* __restrict__ srcs, int gE)
{
    __shared__ __hip_bfloat16 bufA[64 * TSTR];
    __shared__ __hip_bfloat16 bufB[64 * TSTR];
    if (blockIdx.x < gE) {
        int is64 = detect_is64(ei);
        int e = blockIdx.x * 256 + threadIdx.x;
        if (e < E) {
            int s = is64 ? ei[2 * e]         : ei[e];
            int d = is64 ? ei[2 * E + 2 * e] : ei[E + e];
            int pos = atomicAdd(&cursor[d], 1);
            srcs[pos] = s;
        }
    } else {
        gemm_body(blockIdx.x - gE, bufA, bufB, A, Wt, bq, bk, bv, bs, qb, kv, skipb, M);
    }
}

// ---------------------------------------------------------------------------
// attn: 2 nodes/wave (half-waves), lane lh owns dims [4lh,4lh+4).
// Head = 4 lanes -> 2-step shuffle reduce. Batch-8 edges in flight.
__device__ inline void store4(float* base, size_t off, float o0, float o1, float o2, float o3) {
    *(float4*)(base + off) = make_float4(o0, o1, o2, o3);
}
__device__ inline void store4(__hip_bfloat16* base, size_t off, float o0, float o1, float o2, float o3) {
    __hip_bfloat162 h0 = pack2(o0, o1), h1 = pack2(o2, o3);
    float2 st; st.x = *(float*)&h0; st.y = *(float*)&h1;
    *(float2*)(base + off) = st;
}

template <typename OutT>
__global__ __launch_bounds__(256) void attn_agg(
    const __hip_bfloat16* __restrict__ qb, const __hip_bfloat16* __restrict__ kv,
    const int* __restrict__ row_ptr, const int* __restrict__ srcs,
    const __hip_bfloat16* __restrict__ skip, const __hip_bfloat16* __restrict__ residb,
    const float* __restrict__ a_ptr, OutT* __restrict__ out, int Nn) {
    int tid = threadIdx.x;
    int lane = tid & 63;
    int half = lane >> 5;
    int lh = lane & 31;
    int n = blockIdx.x * 8 + (tid >> 6) * 2 + half;
    bool valid = (n < Nn);
    int nc = valid ? n : (Nn - 1);
    const float a = a_ptr[0];

    float2 qraw = *(const float2*)(qb + (size_t)nc * D + 4 * lh);
    __hip_bfloat162 q01 = *(__hip_bfloat162*)&qraw.x;
    __hip_bfloat162 q23 = *(__hip_bfloat162*)&qraw.y;
    float q0 = __bfloat162float(q01.x) * SCALE, q1 = __bfloat162float(q01.y) * SCALE;
    float q2 = __bfloat162float(q23.x) * SCALE, q3 = __bfloat162float(q23.y) * SCALE;

    float m = NEG_BIG, s = 0.f, A0 = 0.f, A1 = 0.f, A2 = 0.f, A3 = 0.f;

    int beg = row_ptr[nc];
    int end = valid ? row_ptr[nc + 1] : beg;
    int cnt = end - beg;
    int cmax = max(cnt, __shfl_xor(cnt, 32));
    int last = (cnt > 0) ? (end - 1) : 0;     // safe clamp index into srcs

    const float4* kvp4 = (const float4*)kv;   // 32 float4 per row

    for (int t = 0; t < cmax; t += 8) {
        float4 f[8];
        float sc[8];
        #pragma unroll
        for (int i = 0; i < 8; ++i) {
            int j = beg + t + i;
            int jj = (j < last) ? j : last;
            int src = srcs[jj];
            f[i] = kvp4[(size_t)src * 32 + lh];
        }
        #pragma unroll
        for (int i = 0; i < 8; ++i) {
            __hip_bfloat162 k01 = *(__hip_bfloat162*)&f[i].x;
            __hip_bfloat162 k23 = *(__hip_bfloat162*)&f[i].y;
            float p = q0 * __bfloat162float(k01.x) + q1 * __bfloat162float(k01.y)
                    + q2 * __bfloat162float(k23.x) + q3 * __bfloat162float(k23.y);
            p += __shfl_xor(p, 1);
            p += __shfl_xor(p, 2);
            sc[i] = (t + i < cnt) ? p : NEG_BIG;
        }
        float nm = m;
        #pragma unroll
        for (int i = 0; i < 8; ++i) nm = fmaxf(nm, sc[i]);
        float corr = __expf(m - nm);
        A0 *= corr; A1 *= corr; A2 *= corr; A3 *= corr; s *= corr;
        #pragma unroll
        for (int i = 0; i < 8; ++i) {
            float wgt = __expf(sc[i] - nm);
            __hip_bfloat162 v01 = *(__hip_bfloat162*)&f[i].z;
            __hip_bfloat162 v23 = *(__hip_bfloat162*)&f[i].w;
            A0 += wgt * __bfloat162float(v01.x);
            A1 += wgt * __bfloat162float(v01.y);
            A2 += wgt * __bfloat162float(v23.x);
            A3 += wgt * __bfloat162float(v23.y);
            s += wgt;
        }
        m = nm;
    }

    if (!valid) return;
    float inv = (cnt > 0) ? 1.f / s : 0.f;
    float2 skr = *(const float2*)(skip + (size_t)n * D + 4 * lh);
    __hip_bfloat162 s01 = *(__hip_bfloat162*)&skr.x;
    __hip_bfloat162 s23 = *(__hip_bfloat162*)&skr.y;
    float o0 = A0 * inv + __bfloat162float(s01.x);
    float o1 = A1 * inv + __bfloat162float(s01.y);
    float o2 = A2 * inv + __bfloat162float(s23.x);
    float o3 = A3 * inv + __bfloat162float(s23.y);
    if (residb) {
        float2 rr = *(const float2*)(residb + (size_t)n * D + 4 * lh);
        __hip_bfloat162 r01 = *(__hip_bfloat162*)&rr.x;
        __hip_bfloat162 r23 = *(__hip_bfloat162*)&rr.y;
        o0 += __bfloat162float(r01.x);
        o1 += __bfloat162float(r01.y);
        o2 += __bfloat162float(r23.x);
        o3 += __bfloat162float(r23.y);
    }
    o0 = (o0 >= 0.f) ? o0 : a * o0;
    o1 = (o1 >= 0.f) ? o1 : a * o1;
    o2 = (o2 >= 0.f) ? o2 : a * o2;
    o3 = (o3 >= 0.f) ? o3 : a * o3;
    store4(out, (size_t)n * D + 4 * lh, o0, o1, o2, o3);
}

// ---------------------------------------------------------------------------
extern "C" void kernel_launch(void* const* d_in, const int* in_sizes, int n_in,
                              void* d_out, int out_size, void* d_ws, size_t ws_size,
                              hipStream_t stream) {
    const float* x  = (const float*)d_in[0];
    const int*   ei = (const int*)d_in[1];
    const float* a  = (const float*)d_in[2];
    const float* Wq1 = (const float*)d_in[3];  const float* bq1 = (const float*)d_in[4];
    const float* Wk1 = (const float*)d_in[5];  const float* bk1 = (const float*)d_in[6];
    const float* Wv1 = (const float*)d_in[7];  const float* bv1 = (const float*)d_in[8];
    const float* Ws1 = (const float*)d_in[9];  const float* bs1 = (const float*)d_in[10];
    const float* Wq2 = (const float*)d_in[11]; const float* bq2 = (const float*)d_in[12];
    const float* Wk2 = (const float*)d_in[13]; const float* bk2 = (const float*)d_in[14];
    const float* Wv2 = (const float*)d_in[15]; const float* bv2 = (const float*)d_in[16];
    const float* Ws2 = (const float*)d_in[17]; const float* bs2 = (const float*)d_in[18];

    const int N = in_sizes[0] / D;        // 100000
    const int E = in_sizes[1] / 2;        // 1000000
    const size_t NF = (size_t)N * D;

    char* wp = (char*)d_ws;
    __hip_bfloat16* xb    = (__hip_bfloat16*)wp; wp += NF * 2;
    __hip_bfloat16* h1b   = (__hip_bfloat16*)wp; wp += NF * 2;
    __hip_bfloat16* qb    = (__hip_bfloat16*)wp; wp += NF * 2;
    __hip_bfloat16* kv    = (__hip_bfloat16*)wp; wp += NF * 4;
    __hip_bfloat16* skipb = (__hip_bfloat16*)wp; wp += NF * 2;
    __hip_bfloat16* WtP   = (__hip_bfloat16*)wp; wp += 2 * 512 * 128 * 2;
    int* deg     = (int*)wp;  wp += (size_t)N * 4;
    int* row_ptr = (int*)wp;  wp += (size_t)(N + 64) * 4;
    int* cursor  = (int*)wp;  wp += (size_t)N * 4;
    int* bsum    = (int*)wp;  wp += 1024 * 4;
    int* boff    = (int*)wp;  wp += 1024 * 4;
    int* srcs    = (int*)wp;  wp += (size_t)E * 4;
    float* out   = (float*)d_out;

    const int TB = 256;
    int gN = (N + TB - 1) / TB;
    int gE = (E + TB - 1) / TB;
    int NB = (N + 1023) / 1024;
    int gGemm = (N + 63) / 64;
    int gAttn = (N + 7) / 8;
    int n4 = (int)(NF / 4);
    int gCvt = (n4 + TB - 1) / TB;

    PackArgs pa;
    pa.w[0] = Wq1; pa.w[1] = Wk1; pa.w[2] = Wv1; pa.w[3] = Ws1;
    pa.w[4] = Wq2; pa.w[5] = Wk2; pa.w[6] = Wv2; pa.w[7] = Ws2;

    // ---- deg = 0 (memset node), then fused prep: count | pack_w | x->bf16
    hipMemsetAsync(deg, 0, (size_t)N * 4, stream);
    hipLaunchKernelGGL(prep, dim3(gE + 8 + gCvt), dim3(TB), 0, stream,
                       pa, WtP, x, xb, n4, ei, E, deg, gE);

    // ---- CSR scan ----
    hipLaunchKernelGGL(scan_blocks, dim3(NB), dim3(1024), 0, stream, deg, row_ptr, bsum, N);
    hipLaunchKernelGGL(scan_bsum, dim3(1), dim3(1024), 0, stream, bsum, boff, NB, row_ptr, N);
    hipLaunchKernelGGL(add_offsets, dim3(gN), dim3(TB), 0, stream, row_ptr, cursor, boff, N);

    // ---- layer-1 GEMM overlapped with edge scatter ----
    hipLaunchKernelGGL(gemm_scatter, dim3(gE + gGemm), dim3(TB), 0, stream,
                       xb, WtP, bq1, bk1, bv1, bs1, qb, kv, skipb, N,
                       ei, E, cursor, srcs, gE);
    hipLaunchKernelGGL(attn_agg<__hip_bfloat16>, dim3(gAttn), dim3(TB), 0, stream,
                       qb, kv, row_ptr, srcs, skipb, (const __hip_bfloat16*)nullptr, a, h1b, N);

    // ---- layer 2 ----
    hipLaunchKernelGGL(gemm_mfma, dim3(gGemm), dim3(TB), 0, stream,
                       h1b, WtP + 512 * 128, bq2, bk2, bv2, bs2, qb, kv, skipb, N);
    hipLaunchKernelGGL(attn_agg<float>, dim3(gAttn), dim3(TB), 0, stream,
                       qb, kv, row_ptr, srcs, skipb, xb, a, out, N);
}

// Round 8
// 524.829 us; speedup vs baseline: 1.1749x; 1.0818x over previous
//
#include <hip/hip_runtime.h>
#include <hip/hip_bf16.h>
#include <math.h>

#define D 128
#define SCALE 0.25f
#define NEG_BIG (-1e30f)
#define SLOTS 32

typedef __attribute__((ext_vector_type(8))) short bf16x8;
typedef __attribute__((ext_vector_type(4))) float f32x4;

__device__ inline __hip_bfloat162 pack2(float a, float b) {
    __hip_bfloat162 h;
    h.x = __float2bfloat16(a);
    h.y = __float2bfloat16(b);
    return h;
}

// int64 vs int32 edge_index: int64 little-endian high words (odd int32s) are
// all zero; int32 layout puts random node ids there. Per-wave ballot.
__device__ inline int detect_is64(const int* __restrict__ ei) {
    int lane = threadIdx.x & 63;
    int v = ei[2 * lane + 1];
    unsigned long long b = __ballot(v != 0);
    return b == 0ULL;
}

// ---------------------------------------------------------------------------
// prep: blocks [0,gE) scatter edges into slots (1 atomic/edge — the only
// atomic pass); [gE,gE+8) pack weights; rest convert x->bf16.
// deg/ovfcnt/slots pre-zeroed by one memset.
struct PackArgs { const float* w[8]; };

__global__ __launch_bounds__(256) void prep(
    PackArgs pa, __hip_bfloat16* __restrict__ WtP,
    const float* __restrict__ x, __hip_bfloat16* __restrict__ xb, int n4,
    const int* __restrict__ ei, int E,
    int* __restrict__ deg, int* __restrict__ slots,
    unsigned long long* __restrict__ ovf, int* __restrict__ ovfcnt, int gE)
{
    int b = blockIdx.x;
    int tid = threadIdx.x;
    if (b < gE) {
        int is64 = detect_is64(ei);
        int e = b * 256 + tid;
        if (e < E) {
            int s = is64 ? ei[2 * e]         : ei[e];
            int d = is64 ? ei[2 * E + 2 * e] : ei[E + e];
            int pos = atomicAdd(&deg[d], 1);
            if (pos < SLOTS) {
                slots[d * SLOTS + pos] = s;
            } else {
                int op = atomicAdd(ovfcnt, 1);
                ovf[op] = ((unsigned long long)(unsigned)d << 32) | (unsigned)s;
            }
        }
    } else if (b < gE + 8) {
        int w = b - gE;
        const float* W = pa.w[w];
        __hip_bfloat16* dst = WtP + (size_t)w * 128 * 128;
        for (int idx = tid; idx < 128 * 128; idx += 256) {
            int c = idx & 127, k = idx >> 7;
            dst[(size_t)c * 128 + k] = __float2bfloat16(W[(size_t)k * 128 + c]);
        }
    } else {
        int i = (b - gE - 8) * 256 + tid;
        if (i < n4) {
            float4 v = ((const float4*)x)[i];
            ((__hip_bfloat162*)xb)[2 * i]     = pack2(v.x, v.y);
            ((__hip_bfloat162*)xb)[2 * i + 1] = pack2(v.z, v.w);
        }
    }
}

// ---------------------------------------------------------------------------
// GEMM: swapped-operand MFMA; LDS-staged coalesced epilogue.
// kv layout: row n = 32 groups of 8: group g = [k4g..k4g+3, v4g..v4g+3].
#define TSTR 136

__global__ __launch_bounds__(256) void gemm_mfma(
    const __hip_bfloat16* __restrict__ A, const __hip_bfloat16* __restrict__ Wt,
    const float* __restrict__ bq, const float* __restrict__ bk,
    const float* __restrict__ bv, const float* __restrict__ bs,
    __hip_bfloat16* __restrict__ qb, __hip_bfloat16* __restrict__ kv,
    __hip_bfloat16* __restrict__ skipb, int M)
{
    __shared__ __hip_bfloat16 bufA[64 * TSTR];
    __shared__ __hip_bfloat16 bufB[64 * TSTR];

    const int tid = threadIdx.x;
    const int w = tid >> 6, lane = tid & 63;
    const int wr = w >> 1, wc = w & 1;
    const int blk0 = blockIdx.x * 64;
    const int rowBase = blk0 + wr * 32;
    const int l16 = lane & 15;
    const int quad = lane >> 4;

    bf16x8 xfrag[2][4];
    #pragma unroll
    for (int i = 0; i < 2; ++i) {
        int r = rowBase + i * 16 + l16;
        if (r >= M) r = M - 1;
        #pragma unroll
        for (int kb = 0; kb < 4; ++kb)
            xfrag[i][kb] = *(const bf16x8*)(A + (size_t)r * D + kb * 32 + quad * 8);
    }

    const float* biases[4] = {bq, bk, bv, bs};

    for (int cb = 0; cb < 4; ++cb) {
        const __hip_bfloat16* Wblk = Wt + (size_t)cb * 128 * 128;
        f32x4 acc[2][4];
        #pragma unroll
        for (int i = 0; i < 2; i++)
            #pragma unroll
            for (int jt = 0; jt < 4; jt++) acc[i][jt] = (f32x4){0.f, 0.f, 0.f, 0.f};

        #pragma unroll
        for (int kb = 0; kb < 4; ++kb) {
            const int k0 = kb * 32 + quad * 8;
            #pragma unroll
            for (int jt = 0; jt < 4; ++jt) {
                int c = wc * 64 + jt * 16 + l16;
                bf16x8 wfrag = *(const bf16x8*)(Wblk + (size_t)c * D + k0);
                acc[0][jt] = __builtin_amdgcn_mfma_f32_16x16x32_bf16(wfrag, xfrag[0][kb], acc[0][jt], 0, 0, 0);
                acc[1][jt] = __builtin_amdgcn_mfma_f32_16x16x32_bf16(wfrag, xfrag[1][kb], acc[1][jt], 0, 0, 0);
            }
        }

        __hip_bfloat16* dst = (cb == 2) ? bufB : bufA;
        const float* bias = biases[cb];
        #pragma unroll
        for (int jt = 0; jt < 4; ++jt) {
            int c0 = wc * 64 + jt * 16 + quad * 4;
            float4 bb = *(const float4*)(bias + c0);
            #pragma unroll
            for (int i = 0; i < 2; ++i) {
                int lrow = wr * 32 + i * 16 + l16;
                f32x4 vv = acc[i][jt];
                __hip_bfloat162 h0 = pack2(vv[0] + bb.x, vv[1] + bb.y);
                __hip_bfloat162 h1 = pack2(vv[2] + bb.z, vv[3] + bb.w);
                float2 st; st.x = *(float*)&h0; st.y = *(float*)&h1;
                *(float2*)(&dst[lrow * TSTR + c0]) = st;
            }
        }

        if (cb == 1) continue;

        __syncthreads();

        if (cb == 0 || cb == 3) {
            __hip_bfloat16* gout = (cb == 0) ? qb : skipb;
            #pragma unroll
            for (int it = 0; it < 4; ++it) {
                int lrow = it * 16 + (tid >> 4);
                int grow = blk0 + lrow;
                if (grow < M) {
                    float4 vv = *(const float4*)(&bufA[lrow * TSTR + (tid & 15) * 8]);
                    *(float4*)(gout + (size_t)grow * D + (tid & 15) * 8) = vv;
                }
            }
        } else {
            #pragma unroll
            for (int it = 0; it < 8; ++it) {
                int lrow = it * 8 + (tid >> 5);
                int grow = blk0 + lrow;
                int g = tid & 31;
                if (grow < M) {
                    float2 kk = *(const float2*)(&bufA[lrow * TSTR + g * 4]);
                    float2 vv = *(const float2*)(&bufB[lrow * TSTR + g * 4]);
                    float4 o; o.x = kk.x; o.y = kk.y; o.z = vv.x; o.w = vv.y;
                    *(float4*)(kv + (size_t)grow * 256 + g * 8) = o;
                }
            }
        }
        __syncthreads();
    }
}

// ---------------------------------------------------------------------------
// attn: 2 nodes/wave, lane lh owns dims [4lh,4lh+4). Slot-row CSR:
// beg = n*32, cnt = deg[n]; rare deg>32 handled by overflow-list scan.
__device__ inline void store4(float* base, size_t off, float o0, float o1, float o2, float o3) {
    *(float4*)(base + off) = make_float4(o0, o1, o2, o3);
}
__device__ inline void store4(__hip_bfloat16* base, size_t off, float o0, float o1, float o2, float o3) {
    __hip_bfloat162 h0 = pack2(o0, o1), h1 = pack2(o2, o3);
    float2 st; st.x = *(float*)&h0; st.y = *(float*)&h1;
    *(float2*)(base + off) = st;
}

template <typename OutT>
__global__ __launch_bounds__(256) void attn_agg(
    const __hip_bfloat16* __restrict__ qb, const __hip_bfloat16* __restrict__ kv,
    const int* __restrict__ deg, const int* __restrict__ slots,
    const unsigned long long* __restrict__ ovf, const int* __restrict__ ovfcnt,
    const __hip_bfloat16* __restrict__ skip, const __hip_bfloat16* __restrict__ residb,
    const float* __restrict__ a_ptr, OutT* __restrict__ out, int Nn) {
    int tid = threadIdx.x;
    int lane = tid & 63;
    int half = lane >> 5;
    int lh = lane & 31;
    int n = blockIdx.x * 8 + (tid >> 6) * 2 + half;
    bool valid = (n < Nn);
    int nc = valid ? n : (Nn - 1);
    const float a = a_ptr[0];

    float2 qraw = *(const float2*)(qb + (size_t)nc * D + 4 * lh);
    __hip_bfloat162 q01 = *(__hip_bfloat162*)&qraw.x;
    __hip_bfloat162 q23 = *(__hip_bfloat162*)&qraw.y;
    float q0 = __bfloat162float(q01.x) * SCALE, q1 = __bfloat162float(q01.y) * SCALE;
    float q2 = __bfloat162float(q23.x) * SCALE, q3 = __bfloat162float(q23.y) * SCALE;

    float m = NEG_BIG, s = 0.f, A0 = 0.f, A1 = 0.f, A2 = 0.f, A3 = 0.f;

    int cnt = valid ? deg[nc] : 0;
    int cmain = min(cnt, SLOTS);
    int cmax = max(cmain, __shfl_xor(cmain, 32));
    int beg = nc * SLOTS;

    const float4* kvp4 = (const float4*)kv;   // 32 float4 per row

    for (int t = 0; t < cmax; t += 8) {
        float4 f[8];
        float sc[8];
        #pragma unroll
        for (int i = 0; i < 8; ++i) {
            int src = slots[beg + t + i];        // slot row zero-padded: safe
            f[i] = kvp4[(size_t)src * 32 + lh];
        }
        #pragma unroll
        for (int i = 0; i < 8; ++i) {
            __hip_bfloat162 k01 = *(__hip_bfloat162*)&f[i].x;
            __hip_bfloat162 k23 = *(__hip_bfloat162*)&f[i].y;
            float p = q0 * __bfloat162float(k01.x) + q1 * __bfloat162float(k01.y)
                    + q2 * __bfloat162float(k23.x) + q3 * __bfloat162float(k23.y);
            p += __shfl_xor(p, 1);
            p += __shfl_xor(p, 2);
            sc[i] = (t + i < cmain) ? p : NEG_BIG;
        }
        float nm = m;
        #pragma unroll
        for (int i = 0; i < 8; ++i) nm = fmaxf(nm, sc[i]);
        float corr = __expf(m - nm);
        A0 *= corr; A1 *= corr; A2 *= corr; A3 *= corr; s *= corr;
        #pragma unroll
        for (int i = 0; i < 8; ++i) {
            float wgt = __expf(sc[i] - nm);
            __hip_bfloat162 v01 = *(__hip_bfloat162*)&f[i].z;
            __hip_bfloat162 v23 = *(__hip_bfloat162*)&f[i].w;
            A0 += wgt * __bfloat162float(v01.x);
            A1 += wgt * __bfloat162float(v01.y);
            A2 += wgt * __bfloat162float(v23.x);
            A3 += wgt * __bfloat162float(v23.y);
            s += wgt;
        }
        m = nm;
    }

    // rare overflow (deg > 32): linear scan of overflow list
    if (__any(cnt > SLOTS)) {
        int oc = *ovfcnt;
        for (int i = 0; i < oc; ++i) {
            unsigned long long e = ovf[i];
            int dd = (int)(e >> 32);
            int ss = (int)(e & 0xffffffffULL);
            bool take = (dd == nc) && (cnt > SLOTS) && valid;
            float4 fo = kvp4[(size_t)ss * 32 + lh];
            __hip_bfloat162 k01 = *(__hip_bfloat162*)&fo.x;
            __hip_bfloat162 k23 = *(__hip_bfloat162*)&fo.y;
            float p = q0 * __bfloat162float(k01.x) + q1 * __bfloat162float(k01.y)
                    + q2 * __bfloat162float(k23.x) + q3 * __bfloat162float(k23.y);
            p += __shfl_xor(p, 1);
            p += __shfl_xor(p, 2);
            float sce = take ? p : NEG_BIG;
            float nm = fmaxf(m, sce);
            float corr = __expf(m - nm);
            float wgt = take ? __expf(sce - nm) : 0.f;
            __hip_bfloat162 v01 = *(__hip_bfloat162*)&fo.z;
            __hip_bfloat162 v23 = *(__hip_bfloat162*)&fo.w;
            A0 = A0 * corr + wgt * __bfloat162float(v01.x);
            A1 = A1 * corr + wgt * __bfloat162float(v01.y);
            A2 = A2 * corr + wgt * __bfloat162float(v23.x);
            A3 = A3 * corr + wgt * __bfloat162float(v23.y);
            s = s * corr + wgt;
            m = nm;
        }
    }

    if (!valid) return;
    float inv = (cnt > 0) ? 1.f / s : 0.f;
    float2 skr = *(const float2*)(skip + (size_t)n * D + 4 * lh);
    __hip_bfloat162 s01 = *(__hip_bfloat162*)&skr.x;
    __hip_bfloat162 s23 = *(__hip_bfloat162*)&skr.y;
    float o0 = A0 * inv + __bfloat162float(s01.x);
    float o1 = A1 * inv + __bfloat162float(s01.y);
    float o2 = A2 * inv + __bfloat162float(s23.x);
    float o3 = A3 * inv + __bfloat162float(s23.y);
    if (residb) {
        float2 rr = *(const float2*)(residb + (size_t)n * D + 4 * lh);
        __hip_bfloat162 r01 = *(__hip_bfloat162*)&rr.x;
        __hip_bfloat162 r23 = *(__hip_bfloat162*)&rr.y;
        o0 += __bfloat162float(r01.x);
        o1 += __bfloat162float(r01.y);
        o2 += __bfloat162float(r23.x);
        o3 += __bfloat162float(r23.y);
    }
    o0 = (o0 >= 0.f) ? o0 : a * o0;
    o1 = (o1 >= 0.f) ? o1 : a * o1;
    o2 = (o2 >= 0.f) ? o2 : a * o2;
    o3 = (o3 >= 0.f) ? o3 : a * o3;
    store4(out, (size_t)n * D + 4 * lh, o0, o1, o2, o3);
}

// ---------------------------------------------------------------------------
extern "C" void kernel_launch(void* const* d_in, const int* in_sizes, int n_in,
                              void* d_out, int out_size, void* d_ws, size_t ws_size,
                              hipStream_t stream) {
    const float* x  = (const float*)d_in[0];
    const int*   ei = (const int*)d_in[1];
    const float* a  = (const float*)d_in[2];
    const float* Wq1 = (const float*)d_in[3];  const float* bq1 = (const float*)d_in[4];
    const float* Wk1 = (const float*)d_in[5];  const float* bk1 = (const float*)d_in[6];
    const float* Wv1 = (const float*)d_in[7];  const float* bv1 = (const float*)d_in[8];
    const float* Ws1 = (const float*)d_in[9];  const float* bs1 = (const float*)d_in[10];
    const float* Wq2 = (const float*)d_in[11]; const float* bq2 = (const float*)d_in[12];
    const float* Wk2 = (const float*)d_in[13]; const float* bk2 = (const float*)d_in[14];
    const float* Wv2 = (const float*)d_in[15]; const float* bv2 = (const float*)d_in[16];
    const float* Ws2 = (const float*)d_in[17]; const float* bs2 = (const float*)d_in[18];

    const int N = in_sizes[0] / D;        // 100000
    const int E = in_sizes[1] / 2;        // 1000000
    const size_t NF = (size_t)N * D;

    char* wp = (char*)d_ws;
    __hip_bfloat16* xb    = (__hip_bfloat16*)wp; wp += NF * 2;
    __hip_bfloat16* h1b   = (__hip_bfloat16*)wp; wp += NF * 2;
    __hip_bfloat16* qb    = (__hip_bfloat16*)wp; wp += NF * 2;
    __hip_bfloat16* kv    = (__hip_bfloat16*)wp; wp += NF * 4;
    __hip_bfloat16* skipb = (__hip_bfloat16*)wp; wp += NF * 2;
    __hip_bfloat16* WtP   = (__hip_bfloat16*)wp; wp += 2 * 512 * 128 * 2;
    // zero-initialized region: deg | ovfcnt(pad 64B) | slots   (one memset)
    int* deg    = (int*)wp;                wp += (size_t)N * 4;
    int* ovfcnt = (int*)wp;                wp += 64;
    int* slots  = (int*)wp;                wp += (size_t)N * SLOTS * 4;
    size_t zbytes = (size_t)N * 4 + 64 + (size_t)N * SLOTS * 4;
    unsigned long long* ovf = (unsigned long long*)wp; wp += (size_t)E * 8;
    float* out = (float*)d_out;

    const int TB = 256;
    int gE = (E + TB - 1) / TB;
    int gGemm = (N + 63) / 64;
    int gAttn = (N + 7) / 8;
    int n4 = (int)(NF / 4);
    int gCvt = (n4 + TB - 1) / TB;

    PackArgs pa;
    pa.w[0] = Wq1; pa.w[1] = Wk1; pa.w[2] = Wv1; pa.w[3] = Ws1;
    pa.w[4] = Wq2; pa.w[5] = Wk2; pa.w[6] = Wv2; pa.w[7] = Ws2;

    // ---- zero deg/ovfcnt/slots, then fused prep: scatter | pack_w | x->bf16
    hipMemsetAsync(deg, 0, zbytes, stream);
    hipLaunchKernelGGL(prep, dim3(gE + 8 + gCvt), dim3(TB), 0, stream,
                       pa, WtP, x, xb, n4, ei, E, deg, slots, ovf, ovfcnt, gE);

    // ---- layer 1 ----
    hipLaunchKernelGGL(gemm_mfma, dim3(gGemm), dim3(TB), 0, stream,
                       xb, WtP, bq1, bk1, bv1, bs1, qb, kv, skipb, N);
    hipLaunchKernelGGL(attn_agg<__hip_bfloat16>, dim3(gAttn), dim3(TB), 0, stream,
                       qb, kv, deg, slots, ovf, ovfcnt, skipb,
                       (const __hip_bfloat16*)nullptr, a, h1b, N);

    // ---- layer 2 ----
    hipLaunchKernelGGL(gemm_mfma, dim3(gGemm), dim3(TB), 0, stream,
                       h1b, WtP + 512 * 128, bq2, bk2, bv2, bs2, qb, kv, skipb, N);
    hipLaunchKernelGGL(attn_agg<float>, dim3(gAttn), dim3(TB), 0, stream,
                       qb, kv, deg, slots, ovf, ovfcnt, skipb, xb, a, out, N);
}

// Round 9
// 516.355 us; speedup vs baseline: 1.1942x; 1.0164x over previous
//
#include <hip/hip_runtime.h>
#include <hip/hip_bf16.h>
#include <math.h>

#define D 128
#define SCALE 0.25f
#define NEG_BIG (-1e30f)
#define SLOTS 32

typedef __attribute__((ext_vector_type(8))) short bf16x8;
typedef __attribute__((ext_vector_type(4))) float f32x4;

__device__ inline __hip_bfloat162 pack2(float a, float b) {
    __hip_bfloat162 h;
    h.x = __float2bfloat16(a);
    h.y = __float2bfloat16(b);
    return h;
}

// int64 vs int32 edge_index: int64 little-endian high words (odd int32s) are
// all zero; int32 layout puts random node ids there. Per-wave ballot.
__device__ inline int detect_is64(const int* __restrict__ ei) {
    int lane = threadIdx.x & 63;
    int v = ei[2 * lane + 1];
    unsigned long long b = __ballot(v != 0);
    return b == 0ULL;
}

// ---------------------------------------------------------------------------
// prep_light: blocks [0,8) pack weights; rest convert x->bf16.
struct PackArgs { const float* w[8]; };

__global__ __launch_bounds__(256) void prep_light(
    PackArgs pa, __hip_bfloat16* __restrict__ WtP,
    const float* __restrict__ x, __hip_bfloat16* __restrict__ xb, int n4)
{
    int b = blockIdx.x;
    int tid = threadIdx.x;
    if (b < 8) {
        const float* W = pa.w[b];
        __hip_bfloat16* dst = WtP + (size_t)b * 128 * 128;
        for (int idx = tid; idx < 128 * 128; idx += 256) {
            int c = idx & 127, k = idx >> 7;
            dst[(size_t)c * 128 + k] = __float2bfloat16(W[(size_t)k * 128 + c]);
        }
    } else {
        int i = (b - 8) * 256 + tid;
        if (i < n4) {
            float4 v = ((const float4*)x)[i];
            ((__hip_bfloat162*)xb)[2 * i]     = pack2(v.x, v.y);
            ((__hip_bfloat162*)xb)[2 * i + 1] = pack2(v.z, v.w);
        }
    }
}

// ---------------------------------------------------------------------------
// GEMM body: swapped-operand MFMA; LDS-staged coalesced epilogue.
// kv layout: row n = 32 groups of 8: group g = [k4g..k4g+3, v4g..v4g+3].
#define TSTR 136

__device__ __forceinline__ void gemm_body(
    int bx, __hip_bfloat16* bufA, __hip_bfloat16* bufB,
    const __hip_bfloat16* __restrict__ A, const __hip_bfloat16* __restrict__ Wt,
    const float* __restrict__ bq, const float* __restrict__ bk,
    const float* __restrict__ bv, const float* __restrict__ bs,
    __hip_bfloat16* __restrict__ qb, __hip_bfloat16* __restrict__ kv,
    __hip_bfloat16* __restrict__ skipb, int M)
{
    const int tid = threadIdx.x;
    const int w = tid >> 6, lane = tid & 63;
    const int wr = w >> 1, wc = w & 1;
    const int blk0 = bx * 64;
    const int rowBase = blk0 + wr * 32;
    const int l16 = lane & 15;
    const int quad = lane >> 4;

    bf16x8 xfrag[2][4];
    #pragma unroll
    for (int i = 0; i < 2; ++i) {
        int r = rowBase + i * 16 + l16;
        if (r >= M) r = M - 1;
        #pragma unroll
        for (int kb = 0; kb < 4; ++kb)
            xfrag[i][kb] = *(const bf16x8*)(A + (size_t)r * D + kb * 32 + quad * 8);
    }

    const float* biases[4] = {bq, bk, bv, bs};

    for (int cb = 0; cb < 4; ++cb) {
        const __hip_bfloat16* Wblk = Wt + (size_t)cb * 128 * 128;
        f32x4 acc[2][4];
        #pragma unroll
        for (int i = 0; i < 2; i++)
            #pragma unroll
            for (int jt = 0; jt < 4; jt++) acc[i][jt] = (f32x4){0.f, 0.f, 0.f, 0.f};

        #pragma unroll
        for (int kb = 0; kb < 4; ++kb) {
            const int k0 = kb * 32 + quad * 8;
            #pragma unroll
            for (int jt = 0; jt < 4; ++jt) {
                int c = wc * 64 + jt * 16 + l16;
                bf16x8 wfrag = *(const bf16x8*)(Wblk + (size_t)c * D + k0);
                acc[0][jt] = __builtin_amdgcn_mfma_f32_16x16x32_bf16(wfrag, xfrag[0][kb], acc[0][jt], 0, 0, 0);
                acc[1][jt] = __builtin_amdgcn_mfma_f32_16x16x32_bf16(wfrag, xfrag[1][kb], acc[1][jt], 0, 0, 0);
            }
        }

        __hip_bfloat16* dst = (cb == 2) ? bufB : bufA;
        const float* bias = biases[cb];
        #pragma unroll
        for (int jt = 0; jt < 4; ++jt) {
            int c0 = wc * 64 + jt * 16 + quad * 4;
            float4 bb = *(const float4*)(bias + c0);
            #pragma unroll
            for (int i = 0; i < 2; ++i) {
                int lrow = wr * 32 + i * 16 + l16;
                f32x4 vv = acc[i][jt];
                __hip_bfloat162 h0 = pack2(vv[0] + bb.x, vv[1] + bb.y);
                __hip_bfloat162 h1 = pack2(vv[2] + bb.z, vv[3] + bb.w);
                float2 st; st.x = *(float*)&h0; st.y = *(float*)&h1;
                *(float2*)(&dst[lrow * TSTR + c0]) = st;
            }
        }

        if (cb == 1) continue;

        __syncthreads();

        if (cb == 0 || cb == 3) {
            __hip_bfloat16* gout = (cb == 0) ? qb : skipb;
            #pragma unroll
            for (int it = 0; it < 4; ++it) {
                int lrow = it * 16 + (tid >> 4);
                int grow = blk0 + lrow;
                if (grow < M) {
                    float4 vv = *(const float4*)(&bufA[lrow * TSTR + (tid & 15) * 8]);
                    *(float4*)(gout + (size_t)grow * D + (tid & 15) * 8) = vv;
                }
            }
        } else {
            #pragma unroll
            for (int it = 0; it < 8; ++it) {
                int lrow = it * 8 + (tid >> 5);
                int grow = blk0 + lrow;
                int g = tid & 31;
                if (grow < M) {
                    float2 kk = *(const float2*)(&bufA[lrow * TSTR + g * 4]);
                    float2 vv = *(const float2*)(&bufB[lrow * TSTR + g * 4]);
                    float4 o; o.x = kk.x; o.y = kk.y; o.z = vv.x; o.w = vv.y;
                    *(float4*)(kv + (size_t)grow * 256 + g * 8) = o;
                }
            }
        }
        __syncthreads();
    }
}

__global__ __launch_bounds__(256) void gemm_mfma(
    const __hip_bfloat16* __restrict__ A, const __hip_bfloat16* __restrict__ Wt,
    const float* __restrict__ bq, const float* __restrict__ bk,
    const float* __restrict__ bv, const float* __restrict__ bs,
    __hip_bfloat16* __restrict__ qb, __hip_bfloat16* __restrict__ kv,
    __hip_bfloat16* __restrict__ skipb, int M)
{
    __shared__ __hip_bfloat16 bufA[64 * TSTR];
    __shared__ __hip_bfloat16 bufB[64 * TSTR];
    gemm_body(blockIdx.x, bufA, bufB, A, Wt, bq, bk, bv, bs, qb, kv, skipb, M);
}

// ---------------------------------------------------------------------------
// scatter_gemm1: EVERY block first fires its edge-scatter slice (atomics +
// fire-and-forget slot stores drain through the fabric in the background),
// then runs its layer-1 GEMM tile. True overlap, not phases.
__global__ __launch_bounds__(256) void scatter_gemm1(
    const __hip_bfloat16* __restrict__ A, const __hip_bfloat16* __restrict__ Wt,
    const float* __restrict__ bq, const float* __restrict__ bk,
    const float* __restrict__ bv, const float* __restrict__ bs,
    __hip_bfloat16* __restrict__ qb, __hip_bfloat16* __restrict__ kv,
    __hip_bfloat16* __restrict__ skipb, int M,
    const int* __restrict__ ei, int E, int EPB,
    int* __restrict__ deg, int* __restrict__ slots,
    unsigned long long* __restrict__ ovf, int* __restrict__ ovfcnt)
{
    __shared__ __hip_bfloat16 bufA[64 * TSTR];
    __shared__ __hip_bfloat16 bufB[64 * TSTR];

    {   // ---- scatter slice ----
        int is64 = detect_is64(ei);
        int base = blockIdx.x * EPB;
        int lim = base + EPB; if (lim > E) lim = E;
        for (int e = base + threadIdx.x; e < lim; e += 256) {
            int s = is64 ? ei[2 * e]         : ei[e];
            int d = is64 ? ei[2 * E + 2 * e] : ei[E + e];
            int pos = atomicAdd(&deg[d], 1);
            if (pos < SLOTS) {
                slots[d * SLOTS + pos] = s;
            } else {
                int op = atomicAdd(ovfcnt, 1);
                ovf[op] = ((unsigned long long)(unsigned)d << 32) | (unsigned)s;
            }
        }
    }
    gemm_body(blockIdx.x, bufA, bufB, A, Wt, bq, bk, bv, bs, qb, kv, skipb, M);
}

// ---------------------------------------------------------------------------
// attn: 2 nodes/wave, lane lh owns dims [4lh,4lh+4). Slot-row CSR.
// Un-zeroed slot entries may be garbage: clamp gather index (masked anyway).
__device__ inline void store4(float* base, size_t off, float o0, float o1, float o2, float o3) {
    *(float4*)(base + off) = make_float4(o0, o1, o2, o3);
}
__device__ inline void store4(__hip_bfloat16* base, size_t off, float o0, float o1, float o2, float o3) {
    __hip_bfloat162 h0 = pack2(o0, o1), h1 = pack2(o2, o3);
    float2 st; st.x = *(float*)&h0; st.y = *(float*)&h1;
    *(float2*)(base + off) = st;
}

template <typename OutT>
__global__ __launch_bounds__(256) void attn_agg(
    const __hip_bfloat16* __restrict__ qb, const __hip_bfloat16* __restrict__ kv,
    const int* __restrict__ deg, const int* __restrict__ slots,
    const unsigned long long* __restrict__ ovf, const int* __restrict__ ovfcnt,
    const __hip_bfloat16* __restrict__ skip, const __hip_bfloat16* __restrict__ residb,
    const float* __restrict__ a_ptr, OutT* __restrict__ out, int Nn) {
    int tid = threadIdx.x;
    int lane = tid & 63;
    int half = lane >> 5;
    int lh = lane & 31;
    int n = blockIdx.x * 8 + (tid >> 6) * 2 + half;
    bool valid = (n < Nn);
    int nc = valid ? n : (Nn - 1);
    const float a = a_ptr[0];

    float2 qraw = *(const float2*)(qb + (size_t)nc * D + 4 * lh);
    __hip_bfloat162 q01 = *(__hip_bfloat162*)&qraw.x;
    __hip_bfloat162 q23 = *(__hip_bfloat162*)&qraw.y;
    float q0 = __bfloat162float(q01.x) * SCALE, q1 = __bfloat162float(q01.y) * SCALE;
    float q2 = __bfloat162float(q23.x) * SCALE, q3 = __bfloat162float(q23.y) * SCALE;

    float m = NEG_BIG, s = 0.f, A0 = 0.f, A1 = 0.f, A2 = 0.f, A3 = 0.f;

    int cnt = valid ? deg[nc] : 0;
    int cmain = min(cnt, SLOTS);
    int cmax = max(cmain, __shfl_xor(cmain, 32));
    int beg = nc * SLOTS;

    const float4* kvp4 = (const float4*)kv;   // 32 float4 per row

    for (int t = 0; t < cmax; t += 8) {
        float4 f[8];
        float sc[8];
        #pragma unroll
        for (int i = 0; i < 8; ++i) {
            int src = slots[beg + t + i];
            src = ((unsigned)src < (unsigned)Nn) ? src : 0;   // garbage-slot clamp
            f[i] = kvp4[(size_t)src * 32 + lh];
        }
        #pragma unroll
        for (int i = 0; i < 8; ++i) {
            __hip_bfloat162 k01 = *(__hip_bfloat162*)&f[i].x;
            __hip_bfloat162 k23 = *(__hip_bfloat162*)&f[i].y;
            float p = q0 * __bfloat162float(k01.x) + q1 * __bfloat162float(k01.y)
                    + q2 * __bfloat162float(k23.x) + q3 * __bfloat162float(k23.y);
            p += __shfl_xor(p, 1);
            p += __shfl_xor(p, 2);
            sc[i] = (t + i < cmain) ? p : NEG_BIG;
        }
        float nm = m;
        #pragma unroll
        for (int i = 0; i < 8; ++i) nm = fmaxf(nm, sc[i]);
        float corr = __expf(m - nm);
        A0 *= corr; A1 *= corr; A2 *= corr; A3 *= corr; s *= corr;
        #pragma unroll
        for (int i = 0; i < 8; ++i) {
            float wgt = __expf(sc[i] - nm);
            __hip_bfloat162 v01 = *(__hip_bfloat162*)&f[i].z;
            __hip_bfloat162 v23 = *(__hip_bfloat162*)&f[i].w;
            A0 += wgt * __bfloat162float(v01.x);
            A1 += wgt * __bfloat162float(v01.y);
            A2 += wgt * __bfloat162float(v23.x);
            A3 += wgt * __bfloat162float(v23.y);
            s += wgt;
        }
        m = nm;
    }

    if (__any(cnt > SLOTS)) {      // rare overflow (deg > 32)
        int oc = *ovfcnt;
        for (int i = 0; i < oc; ++i) {
            unsigned long long e = ovf[i];
            int dd = (int)(e >> 32);
            int ss = (int)(e & 0xffffffffULL);
            bool take = (dd == nc) && (cnt > SLOTS) && valid;
            ss = ((unsigned)ss < (unsigned)Nn) ? ss : 0;
            float4 fo = kvp4[(size_t)ss * 32 + lh];
            __hip_bfloat162 k01 = *(__hip_bfloat162*)&fo.x;
            __hip_bfloat162 k23 = *(__hip_bfloat162*)&fo.y;
            float p = q0 * __bfloat162float(k01.x) + q1 * __bfloat162float(k01.y)
                    + q2 * __bfloat162float(k23.x) + q3 * __bfloat162float(k23.y);
            p += __shfl_xor(p, 1);
            p += __shfl_xor(p, 2);
            float sce = take ? p : NEG_BIG;
            float nm = fmaxf(m, sce);
            float corr = __expf(m - nm);
            float wgt = take ? __expf(sce - nm) : 0.f;
            __hip_bfloat162 v01 = *(__hip_bfloat162*)&fo.z;
            __hip_bfloat162 v23 = *(__hip_bfloat162*)&fo.w;
            A0 = A0 * corr + wgt * __bfloat162float(v01.x);
            A1 = A1 * corr + wgt * __bfloat162float(v01.y);
            A2 = A2 * corr + wgt * __bfloat162float(v23.x);
            A3 = A3 * corr + wgt * __bfloat162float(v23.y);
            s = s * corr + wgt;
            m = nm;
        }
    }

    if (!valid) return;
    float inv = (cnt > 0) ? 1.f / s : 0.f;
    float2 skr = *(const float2*)(skip + (size_t)n * D + 4 * lh);
    __hip_bfloat162 s01 = *(__hip_bfloat162*)&skr.x;
    __hip_bfloat162 s23 = *(__hip_bfloat162*)&skr.y;
    float o0 = A0 * inv + __bfloat162float(s01.x);
    float o1 = A1 * inv + __bfloat162float(s01.y);
    float o2 = A2 * inv + __bfloat162float(s23.x);
    float o3 = A3 * inv + __bfloat162float(s23.y);
    if (residb) {
        float2 rr = *(const float2*)(residb + (size_t)n * D + 4 * lh);
        __hip_bfloat162 r01 = *(__hip_bfloat162*)&rr.x;
        __hip_bfloat162 r23 = *(__hip_bfloat162*)&rr.y;
        o0 += __bfloat162float(r01.x);
        o1 += __bfloat162float(r01.y);
        o2 += __bfloat162float(r23.x);
        o3 += __bfloat162float(r23.y);
    }
    o0 = (o0 >= 0.f) ? o0 : a * o0;
    o1 = (o1 >= 0.f) ? o1 : a * o1;
    o2 = (o2 >= 0.f) ? o2 : a * o2;
    o3 = (o3 >= 0.f) ? o3 : a * o3;
    store4(out, (size_t)n * D + 4 * lh, o0, o1, o2, o3);
}

// ---------------------------------------------------------------------------
extern "C" void kernel_launch(void* const* d_in, const int* in_sizes, int n_in,
                              void* d_out, int out_size, void* d_ws, size_t ws_size,
                              hipStream_t stream) {
    const float* x  = (const float*)d_in[0];
    const int*   ei = (const int*)d_in[1];
    const float* a  = (const float*)d_in[2];
    const float* Wq1 = (const float*)d_in[3];  const float* bq1 = (const float*)d_in[4];
    const float* Wk1 = (const float*)d_in[5];  const float* bk1 = (const float*)d_in[6];
    const float* Wv1 = (const float*)d_in[7];  const float* bv1 = (const float*)d_in[8];
    const float* Ws1 = (const float*)d_in[9];  const float* bs1 = (const float*)d_in[10];
    const float* Wq2 = (const float*)d_in[11]; const float* bq2 = (const float*)d_in[12];
    const float* Wk2 = (const float*)d_in[13]; const float* bk2 = (const float*)d_in[14];
    const float* Wv2 = (const float*)d_in[15]; const float* bv2 = (const float*)d_in[16];
    const float* Ws2 = (const float*)d_in[17]; const float* bs2 = (const float*)d_in[18];

    const int N = in_sizes[0] / D;        // 100000
    const int E = in_sizes[1] / 2;        // 1000000
    const size_t NF = (size_t)N * D;

    char* wp = (char*)d_ws;
    __hip_bfloat16* xb    = (__hip_bfloat16*)wp; wp += NF * 2;
    __hip_bfloat16* h1b   = (__hip_bfloat16*)wp; wp += NF * 2;
    __hip_bfloat16* qb    = (__hip_bfloat16*)wp; wp += NF * 2;
    __hip_bfloat16* kv    = (__hip_bfloat16*)wp; wp += NF * 4;
    __hip_bfloat16* skipb = (__hip_bfloat16*)wp; wp += NF * 2;
    __hip_bfloat16* WtP   = (__hip_bfloat16*)wp; wp += 2 * 512 * 128 * 2;
    int* deg    = (int*)wp;                wp += (size_t)N * 4;
    int* ovfcnt = (int*)wp;                wp += 64;
    size_t zbytes = (size_t)N * 4 + 64;           // zero deg + ovfcnt only
    int* slots  = (int*)wp;                wp += (size_t)N * SLOTS * 4;
    unsigned long long* ovf = (unsigned long long*)wp; wp += (size_t)E * 8;
    float* out = (float*)d_out;

    const int TB = 256;
    int gGemm = (N + 63) / 64;
    int gAttn = (N + 7) / 8;
    int n4 = (int)(NF / 4);
    int gCvt = (n4 + TB - 1) / TB;
    int EPB = (E + gGemm - 1) / gGemm;    // edges per scatter_gemm1 block

    PackArgs pa;
    pa.w[0] = Wq1; pa.w[1] = Wk1; pa.w[2] = Wv1; pa.w[3] = Ws1;
    pa.w[4] = Wq2; pa.w[5] = Wk2; pa.w[6] = Wv2; pa.w[7] = Ws2;

    hipMemsetAsync(deg, 0, zbytes, stream);
    hipLaunchKernelGGL(prep_light, dim3(8 + gCvt), dim3(TB), 0, stream,
                       pa, WtP, x, xb, n4);

    // ---- layer-1 GEMM with per-block interleaved edge scatter ----
    hipLaunchKernelGGL(scatter_gemm1, dim3(gGemm), dim3(TB), 0, stream,
                       xb, WtP, bq1, bk1, bv1, bs1, qb, kv, skipb, N,
                       ei, E, EPB, deg, slots, ovf, ovfcnt);
    hipLaunchKernelGGL(attn_agg<__hip_bfloat16>, dim3(gAttn), dim3(TB), 0, stream,
                       qb, kv, deg, slots, ovf, ovfcnt, skipb,
                       (const __hip_bfloat16*)nullptr, a, h1b, N);

    // ---- layer 2 ----
    hipLaunchKernelGGL(gemm_mfma, dim3(gGemm), dim3(TB), 0, stream,
                       h1b, WtP + 512 * 128, bq2, bk2, bv2, bs2, qb, kv, skipb, N);
    hipLaunchKernelGGL(attn_agg<float>, dim3(gAttn), dim3(TB), 0, stream,
                       qb, kv, deg, slots, ovf, ovfcnt, skipb, xb, a, out, N);
}